// Round 1
// baseline (650.015 us; speedup 1.0000x reference)
//
#include <hip/hip_runtime.h>

#define B_   64
#define NQ_  1024
#define L_   128
#define E_   8192
#define M_   (B_*NQ_)   // 65536 rows for all node-space GEMMs

// ---------------------------------------------------------------------------
// h[b,q,:] = z0[b,:]  (broadcast init)
// ---------------------------------------------------------------------------
__global__ __launch_bounds__(256) void k_init_h(float* __restrict__ h,
                                                const float* __restrict__ z0) {
    int i4 = blockIdx.x * 256 + threadIdx.x;      // float4 index, 2097152 total
    int f  = i4 * 4;
    int b  = f >> 17;                              // / (NQ_*L_)
    int l4 = (f >> 2) & 31;                        // (f % 128)/4
    const float4* z4 = (const float4*)z0;
    ((float4*)h)[i4] = z4[b * 32 + l4];
}

// ---------------------------------------------------------------------------
// CSR build (single block). Detects int32 vs int64 storage of edge_index.
// Produces: ofs[NQ_+1], tgt_s[E_] (tgt in src-sorted order), a_s[E_], degf[NQ_]
// ---------------------------------------------------------------------------
__global__ __launch_bounds__(1024) void k_csr(const int* __restrict__ ei,
                                              const float* __restrict__ attr,
                                              int* __restrict__ ofs,
                                              int* __restrict__ tgt_s,
                                              float* __restrict__ a_s,
                                              float* __restrict__ degf) {
    __shared__ int cnt[NQ_];
    __shared__ int run[NQ_];
    __shared__ int s_i64;
    int tid = threadIdx.x;
    if (tid == 0) s_i64 = 1;
    for (int q = tid; q < NQ_; q += 1024) cnt[q] = 0;
    __syncthreads();
    if (tid < 100) {                       // int64 LE => high words all zero
        if (ei[2 * tid + 1] != 0) atomicAnd(&s_i64, 0);
    }
    __syncthreads();
    int i64 = s_i64;
    for (int e = tid; e < E_; e += 1024) {
        int s = i64 ? ei[2 * e] : ei[e];
        atomicAdd(&cnt[s], 1);
    }
    __syncthreads();
    if (tid == 0) {
        int acc = 0;
        for (int q = 0; q < NQ_; ++q) { run[q] = acc; acc += cnt[q]; }
    }
    __syncthreads();
    for (int q = tid; q < NQ_; q += 1024) {
        ofs[q]  = run[q];
        degf[q] = (float)cnt[q];
    }
    if (tid == 0) ofs[NQ_] = E_;
    __syncthreads();
    for (int e = tid; e < E_; e += 1024) {
        int s = i64 ? ei[2 * e]        : ei[e];
        int t = i64 ? ei[2 * (E_ + e)] : ei[E_ + e];
        int p = atomicAdd(&run[s], 1);
        tgt_s[p] = t;
        a_s[p]   = attr[e];
    }
}

// ---------------------------------------------------------------------------
// Pre-transpose all 12 weight matrices to k-major [128][128]: wt[m][kk*128+n]
// m = 6*k + {w1a, w1b, w2, n1a, n1b, n2}
// ---------------------------------------------------------------------------
__global__ __launch_bounds__(256) void k_transpose(const float* __restrict__ e_w1,
                                                   const float* __restrict__ e_w2,
                                                   const float* __restrict__ n_w1,
                                                   const float* __restrict__ n_w2,
                                                   float* __restrict__ wt) {
    __shared__ float sT[128][128];     // XOR-swizzled to kill bank conflicts
    int m = blockIdx.x, k = m / 6, j = m % 6;
    const float* src; int ld, off;
    switch (j) {
        case 0: src = e_w1 + k * L_ * 257; ld = 257; off = 0;   break;
        case 1: src = e_w1 + k * L_ * 257; ld = 257; off = 128; break;
        case 2: src = e_w2 + k * L_ * L_;  ld = 128; off = 0;   break;
        case 3: src = n_w1 + k * L_ * 256; ld = 256; off = 0;   break;
        case 4: src = n_w1 + k * L_ * 256; ld = 256; off = 128; break;
        default:src = n_w2 + k * L_ * L_;  ld = 128; off = 0;   break;
    }
    float* dst = wt + m * 16384;
    int tid = threadIdx.x;
    for (int idx = tid; idx < 16384; idx += 256) {   // coalesced read along kk
        int n = idx >> 7, kk = idx & 127;
        sT[kk][n ^ (kk & 31)] = src[n * ld + off + kk];
    }
    __syncthreads();
    for (int idx = tid; idx < 16384; idx += 256) {   // coalesced write along n
        int kk = idx >> 7, n = idx & 127;
        dst[idx] = sT[kk][n ^ (kk & 31)];
    }
}

// ---------------------------------------------------------------------------
// C1 = A @ Wt1,  C2 = A @ Wt2   (M=65536, N=K=128, Wt k-major)
// BM=64, BK=32, 256 threads, thread tile 8x4
// ---------------------------------------------------------------------------
__global__ __launch_bounds__(256) void k_gemm2w(const float* __restrict__ A,
                                                const float* __restrict__ Wt1,
                                                const float* __restrict__ Wt2,
                                                float* __restrict__ C1,
                                                float* __restrict__ C2) {
    __shared__ float sA[32][72];
    __shared__ float sW1[32][128];
    __shared__ float sW2[32][128];
    int tid = threadIdx.x;
    int ty = tid >> 5, tx = tid & 31;
    int rowBase = blockIdx.x * 64;
    float acc1[8][4] = {}, acc2[8][4] = {};
    for (int kb = 0; kb < 128; kb += 32) {
        int lr = tid >> 2;
#pragma unroll
        for (int u = 0; u < 2; ++u) {
            int kg = (tid & 3) + u * 4;
            float4 av = *(const float4*)&A[(rowBase + lr) * 128 + kb + kg * 4];
            sA[kg * 4 + 0][lr] = av.x; sA[kg * 4 + 1][lr] = av.y;
            sA[kg * 4 + 2][lr] = av.z; sA[kg * 4 + 3][lr] = av.w;
        }
#pragma unroll
        for (int it = 0; it < 4; ++it) {
            int f4 = tid + it * 256;
            int kkl = f4 >> 5, n4 = f4 & 31;
            *(float4*)&sW1[kkl][n4 * 4] = *(const float4*)&Wt1[(kb + kkl) * 128 + n4 * 4];
            *(float4*)&sW2[kkl][n4 * 4] = *(const float4*)&Wt2[(kb + kkl) * 128 + n4 * 4];
        }
        __syncthreads();
#pragma unroll 8
        for (int kk = 0; kk < 32; ++kk) {
            float4 a0 = *(const float4*)&sA[kk][ty * 8];
            float4 a1 = *(const float4*)&sA[kk][ty * 8 + 4];
            float a[8] = {a0.x, a0.y, a0.z, a0.w, a1.x, a1.y, a1.z, a1.w};
            float4 w1 = *(const float4*)&sW1[kk][tx * 4];
            float4 w2 = *(const float4*)&sW2[kk][tx * 4];
            float w1a[4] = {w1.x, w1.y, w1.z, w1.w};
            float w2a[4] = {w2.x, w2.y, w2.z, w2.w};
#pragma unroll
            for (int i = 0; i < 8; ++i)
#pragma unroll
                for (int jj = 0; jj < 4; ++jj) {
                    acc1[i][jj] = fmaf(a[i], w1a[jj], acc1[i][jj]);
                    acc2[i][jj] = fmaf(a[i], w2a[jj], acc2[i][jj]);
                }
        }
        __syncthreads();
    }
#pragma unroll
    for (int i = 0; i < 8; ++i) {
        int row = rowBase + ty * 8 + i;
        float4 o1 = {acc1[i][0], acc1[i][1], acc1[i][2], acc1[i][3]};
        float4 o2 = {acc2[i][0], acc2[i][1], acc2[i][2], acc2[i][3]};
        *(float4*)&C1[row * 128 + tx * 4] = o1;
        *(float4*)&C2[row * 128 + tx * 4] = o2;
    }
}

// ---------------------------------------------------------------------------
// C = act( A1@Wt1 [+ A2@Wt2] [+ bias (* degf[row%NQ])] ) [+ C]
// ---------------------------------------------------------------------------
template <bool HAS_A2>
__global__ __launch_bounds__(256) void k_gemm_gen(const float* __restrict__ A1,
                                                  const float* __restrict__ A2,
                                                  const float* __restrict__ Wt1,
                                                  const float* __restrict__ Wt2,
                                                  const float* __restrict__ bias,
                                                  const float* __restrict__ degf,
                                                  int relu, int accum,
                                                  float* __restrict__ C) {
    __shared__ float sA1[32][72];
    __shared__ float sA2[HAS_A2 ? 32 : 1][HAS_A2 ? 72 : 1];
    __shared__ float sW1[32][128];
    __shared__ float sW2[HAS_A2 ? 32 : 1][HAS_A2 ? 128 : 1];
    int tid = threadIdx.x;
    int ty = tid >> 5, tx = tid & 31;
    int rowBase = blockIdx.x * 64;
    float acc[8][4] = {};
    for (int kb = 0; kb < 128; kb += 32) {
        int lr = tid >> 2;
#pragma unroll
        for (int u = 0; u < 2; ++u) {
            int kg = (tid & 3) + u * 4;
            float4 av = *(const float4*)&A1[(rowBase + lr) * 128 + kb + kg * 4];
            sA1[kg * 4 + 0][lr] = av.x; sA1[kg * 4 + 1][lr] = av.y;
            sA1[kg * 4 + 2][lr] = av.z; sA1[kg * 4 + 3][lr] = av.w;
            if (HAS_A2) {
                float4 bv = *(const float4*)&A2[(rowBase + lr) * 128 + kb + kg * 4];
                sA2[kg * 4 + 0][lr] = bv.x; sA2[kg * 4 + 1][lr] = bv.y;
                sA2[kg * 4 + 2][lr] = bv.z; sA2[kg * 4 + 3][lr] = bv.w;
            }
        }
#pragma unroll
        for (int it = 0; it < 4; ++it) {
            int f4 = tid + it * 256;
            int kkl = f4 >> 5, n4 = f4 & 31;
            *(float4*)&sW1[kkl][n4 * 4] = *(const float4*)&Wt1[(kb + kkl) * 128 + n4 * 4];
            if (HAS_A2)
                *(float4*)&sW2[kkl][n4 * 4] = *(const float4*)&Wt2[(kb + kkl) * 128 + n4 * 4];
        }
        __syncthreads();
#pragma unroll 8
        for (int kk = 0; kk < 32; ++kk) {
            float4 a0 = *(const float4*)&sA1[kk][ty * 8];
            float4 a1 = *(const float4*)&sA1[kk][ty * 8 + 4];
            float a[8] = {a0.x, a0.y, a0.z, a0.w, a1.x, a1.y, a1.z, a1.w};
            float4 w1 = *(const float4*)&sW1[kk][tx * 4];
            float w1a[4] = {w1.x, w1.y, w1.z, w1.w};
#pragma unroll
            for (int i = 0; i < 8; ++i)
#pragma unroll
                for (int jj = 0; jj < 4; ++jj)
                    acc[i][jj] = fmaf(a[i], w1a[jj], acc[i][jj]);
            if (HAS_A2) {
                float4 b0 = *(const float4*)&sA2[kk][ty * 8];
                float4 b1v = *(const float4*)&sA2[kk][ty * 8 + 4];
                float bb[8] = {b0.x, b0.y, b0.z, b0.w, b1v.x, b1v.y, b1v.z, b1v.w};
                float4 w2 = *(const float4*)&sW2[kk][tx * 4];
                float w2a[4] = {w2.x, w2.y, w2.z, w2.w};
#pragma unroll
                for (int i = 0; i < 8; ++i)
#pragma unroll
                    for (int jj = 0; jj < 4; ++jj)
                        acc[i][jj] = fmaf(bb[i], w2a[jj], acc[i][jj]);
            }
        }
        __syncthreads();
    }
#pragma unroll
    for (int i = 0; i < 8; ++i) {
        int row = rowBase + ty * 8 + i;
        float scale = degf ? degf[row & (NQ_ - 1)] : 1.0f;
        float4 o;
        float* ov = (float*)&o;
#pragma unroll
        for (int jj = 0; jj < 4; ++jj) {
            float v = acc[i][jj];
            if (bias) v += bias[tx * 4 + jj] * scale;
            if (relu) v = fmaxf(v, 0.0f);
            ov[jj] = v;
        }
        if (accum) {
            float4 c0 = *(const float4*)&C[row * 128 + tx * 4];
            o.x += c0.x; o.y += c0.y; o.z += c0.z; o.w += c0.w;
        }
        *(float4*)&C[row * 128 + tx * 4] = o;
    }
}

// ---------------------------------------------------------------------------
// S[b,q,:] = sum_{e in seg(q)} relu( ci[b,q,:] + cj[b,tgt,:] + a_e*wlast + b1 )
// one block per (b,q), 128 threads (one per l)
// ---------------------------------------------------------------------------
__global__ __launch_bounds__(128) void k_S(const float* __restrict__ ci,
                                           const float* __restrict__ cj,
                                           const int* __restrict__ ofs,
                                           const int* __restrict__ tgt_s,
                                           const float* __restrict__ a_s,
                                           const float* __restrict__ w1k,  // e_w1[k] base
                                           const float* __restrict__ b1k,
                                           float* __restrict__ S) {
    int q = blockIdx.x & (NQ_ - 1);
    int b = blockIdx.x >> 10;
    int l = threadIdx.x;
    float wl  = w1k[l * 257 + 256];
    float b1v = b1k[l];
    int base  = (b * NQ_ + q) * L_;
    float civ = ci[base + l] + b1v;   // fold bias in once
    int st = ofs[q], en = ofs[q + 1];
    float acc = 0.0f;
    for (int idx = st; idx < en; ++idx) {
        int   t = tgt_s[idx];
        float a = a_s[idx];
        float v = civ + cj[(b * NQ_ + t) * L_ + l] + a * wl;
        acc += fmaxf(v, 0.0f);
    }
    S[base + l] = acc;
}

// ---------------------------------------------------------------------------
// In-place LayerNorm over rows of 128, one wave per row
// ---------------------------------------------------------------------------
__global__ __launch_bounds__(256) void k_ln(float* __restrict__ X,
                                            const float* __restrict__ g,
                                            const float* __restrict__ bb) {
    int wave = threadIdx.x >> 6, lane = threadIdx.x & 63;
    int row  = blockIdx.x * 4 + wave;
    int base = row * 128;
    float x0 = X[base + lane], x1 = X[base + 64 + lane];
    float s  = x0 + x1;
    float sq = x0 * x0 + x1 * x1;
#pragma unroll
    for (int o = 32; o > 0; o >>= 1) {
        s  += __shfl_xor(s, o, 64);
        sq += __shfl_xor(sq, o, 64);
    }
    float mean = s * (1.0f / 128.0f);
    float var  = sq * (1.0f / 128.0f) - mean * mean;
    float rs   = rsqrtf(var + 1e-5f);
    X[base + lane]      = (x0 - mean) * rs * g[lane]      + bb[lane];
    X[base + 64 + lane] = (x1 - mean) * rs * g[lane + 64] + bb[lane + 64];
}

// ---------------------------------------------------------------------------
// final mean over q: two-stage
// ---------------------------------------------------------------------------
__global__ __launch_bounds__(128) void k_partial(const float* __restrict__ h,
                                                 float* __restrict__ partial) {
    int c = blockIdx.x;          // 512 = 64 b * 8 chunks
    int b = c >> 3, ch = c & 7;
    float acc = 0.0f;
    int q0 = ch * 128;
    for (int q = q0; q < q0 + 128; ++q)
        acc += h[(b * NQ_ + q) * L_ + threadIdx.x];
    partial[c * 128 + threadIdx.x] = acc;
}

__global__ __launch_bounds__(256) void k_final(const float* __restrict__ partial,
                                               float* __restrict__ out) {
    int i = blockIdx.x * 256 + threadIdx.x;    // 8192
    int b = i >> 7, l = i & 127;
    float s = 0.0f;
#pragma unroll
    for (int c = 0; c < 8; ++c) s += partial[(b * 8 + c) * 128 + l];
    out[i] = s * (1.0f / 1024.0f);
}

// ---------------------------------------------------------------------------
extern "C" void kernel_launch(void* const* d_in, const int* in_sizes, int n_in,
                              void* d_out, int out_size, void* d_ws, size_t ws_size,
                              hipStream_t stream) {
    const float* z0    = (const float*)d_in[0];
    const int*   ei    = (const int*)d_in[1];
    const float* attr  = (const float*)d_in[2];
    const float* e_w1  = (const float*)d_in[4];
    const float* e_b1  = (const float*)d_in[5];
    const float* e_w2  = (const float*)d_in[6];
    const float* e_b2  = (const float*)d_in[7];
    const float* n_w1  = (const float*)d_in[8];
    const float* n_b1  = (const float*)d_in[9];
    const float* ln_g  = (const float*)d_in[10];
    const float* ln_b  = (const float*)d_in[11];
    const float* n_w2  = (const float*)d_in[12];
    const float* n_b2  = (const float*)d_in[13];
    float* out = (float*)d_out;

    const size_t H = (size_t)M_ * L_;           // 8388608 floats per buffer
    float* f    = (float*)d_ws;
    float* h    = f;                            // persistent node features
    float* b1f  = f + H;                        // ci / m_agg
    float* b2f  = f + 2 * H;                    // cj / x
    float* b3f  = f + 3 * H;                    // S (segment sums)
    float* wt   = f + 4 * H;                    // 12 * 16384
    float* part = wt + 12 * 16384;              // 65536
    float* a_s  = part + 65536;                 // 8192
    float* degf = a_s + 8192;                   // 1024
    int*   ofs   = (int*)(degf + 1024);         // 1025
    int*   tgt_s = ofs + 1056;                  // 8192

    k_init_h<<<8192, 256, 0, stream>>>(h, z0);
    k_csr<<<1, 1024, 0, stream>>>(ei, attr, ofs, tgt_s, a_s, degf);
    k_transpose<<<12, 256, 0, stream>>>(e_w1, e_w2, n_w1, n_w2, wt);

    for (int k = 0; k < 2; ++k) {
        const float* wtk = wt + k * 6 * 16384;
        // ci = h @ W1a^T, cj = h @ W1b^T
        k_gemm2w<<<1024, 256, 0, stream>>>(h, wtk, wtk + 16384, b1f, b2f);
        // segment-summed relu hidden
        k_S<<<M_, 128, 0, stream>>>(b1f, b2f, ofs, tgt_s, a_s,
                                    e_w1 + k * L_ * 257, e_b1 + k * L_, b3f);
        // m_agg = S @ e_w2^T + deg*b2   -> b1f
        k_gemm_gen<false><<<1024, 256, 0, stream>>>(b3f, nullptr, wtk + 2 * 16384,
                                                    nullptr, e_b2 + k * L_, degf,
                                                    0, 0, b1f);
        // x = relu(h @ n1a^T + m_agg @ n1b^T + b1) -> b2f
        k_gemm_gen<true><<<1024, 256, 0, stream>>>(h, b1f, wtk + 3 * 16384,
                                                   wtk + 4 * 16384, n_b1 + k * L_,
                                                   nullptr, 1, 0, b2f);
        // LayerNorm in place on b2f
        k_ln<<<M_ / 4, 256, 0, stream>>>(b2f, ln_g + k * L_, ln_b + k * L_);
        // h += x @ n2^T + b2
        k_gemm_gen<false><<<1024, 256, 0, stream>>>(b2f, nullptr, wtk + 5 * 16384,
                                                    nullptr, n_b2 + k * L_, nullptr,
                                                    0, 1, h);
    }
    k_partial<<<512, 128, 0, stream>>>(h, part);
    k_final<<<32, 256, 0, stream>>>(part, out);
}

// Round 2
// 471.847 us; speedup vs baseline: 1.3776x; 1.3776x over previous
//
#include <hip/hip_runtime.h>

#define B_   64
#define NQ_  1024
#define L_   128
#define E_   8192
#define M_   (B_*NQ_)   // 65536 rows

typedef unsigned short u16;
typedef unsigned int   u32;
typedef __attribute__((ext_vector_type(8))) short short8;   // 8 bf16
typedef __attribute__((ext_vector_type(4))) float floatx4;  // MFMA C/D

__device__ __forceinline__ u16 f2bf(float f) {              // RNE fp32->bf16
    union { float f; u32 u; } v; v.f = f;
    return (u16)((v.u + 0x7fffu + ((v.u >> 16) & 1u)) >> 16);
}
__device__ __forceinline__ float bf2f(u16 u) {
    union { u32 u; float f; } v; v.u = ((u32)u) << 16;
    return v.f;
}
__device__ __forceinline__ floatx4 mfma16(short8 a, short8 b, floatx4 c) {
    return __builtin_amdgcn_mfma_f32_16x16x32_bf16(a, b, c, 0, 0, 0);
}
// A/B fragment from global row-major [.][128] bf16 (k contiguous)
__device__ __forceinline__ short8 gfrag(const u16* base, int r0, int kb, int lane) {
    return *(const short8*)(base + (size_t)(r0 + (lane & 15)) * 128 + kb * 32 + (lane >> 4) * 8);
}
#define LDP 136   // padded LDS row stride (shorts): 272B = 17*16 -> 16B aligned, 2-way-conflict only
__device__ __forceinline__ short8 lfrag(const u16* t, int kb, int lane) {
    return *(const short8*)(t + (lane & 15) * LDP + kb * 32 + (lane >> 4) * 8);
}
// C-layout frags (8 n-tiles x 4 regs) -> bf16 LDS tile [16][LDP]
__device__ __forceinline__ void tile_store(u16* t, const floatx4* acc, int lane) {
    int col = lane & 15, qd = lane >> 4;
#pragma unroll
    for (int nt = 0; nt < 8; ++nt)
#pragma unroll
        for (int r = 0; r < 4; ++r)
            t[(qd * 4 + r) * LDP + nt * 16 + col] = f2bf(acc[nt][r]);
}
// LDS tile -> global rows (coalesced 16B stores; wave's 16 rows are contiguous)
__device__ __forceinline__ void tile_flush(const u16* t, u16* g, int lane) {
#pragma unroll
    for (int it = 0; it < 4; ++it) {
        int chunk = it * 64 + lane, row = chunk >> 4, c8 = chunk & 15;
        *(uint4*)(g + (size_t)row * 128 + c8 * 8) = *(const uint4*)(t + row * LDP + c8 * 8);
    }
}

// ---------------------------------------------------------------------------
// h[b,q,:] = z0[b,:]  fp32 + bf16 mirror
// ---------------------------------------------------------------------------
__global__ __launch_bounds__(256) void k_init_h(float* __restrict__ h,
                                                u16* __restrict__ hbf,
                                                const float* __restrict__ z0) {
    int i4 = blockIdx.x * 256 + threadIdx.x;      // float4 index, 2097152 total
    int f  = i4 * 4;
    int b  = f >> 17;
    int l4 = (f >> 2) & 31;
    float4 v = ((const float4*)z0)[b * 32 + l4];
    ((float4*)h)[i4] = v;
    ushort4 u; u.x = f2bf(v.x); u.y = f2bf(v.y); u.z = f2bf(v.z); u.w = f2bf(v.w);
    ((ushort4*)hbf)[i4] = u;
}

// ---------------------------------------------------------------------------
// CSR build (single block), int32/int64 storage auto-detect
// ---------------------------------------------------------------------------
__global__ __launch_bounds__(1024) void k_csr(const int* __restrict__ ei,
                                              const float* __restrict__ attr,
                                              int* __restrict__ ofs,
                                              int* __restrict__ tgt_s,
                                              float* __restrict__ a_s,
                                              float* __restrict__ degf) {
    __shared__ int cnt[NQ_];
    __shared__ int run[NQ_];
    __shared__ int s_i64;
    int tid = threadIdx.x;
    if (tid == 0) s_i64 = 1;
    for (int q = tid; q < NQ_; q += 1024) cnt[q] = 0;
    __syncthreads();
    if (tid < 100) {
        if (ei[2 * tid + 1] != 0) atomicAnd(&s_i64, 0);
    }
    __syncthreads();
    int i64 = s_i64;
    for (int e = tid; e < E_; e += 1024) {
        int s = i64 ? ei[2 * e] : ei[e];
        atomicAdd(&cnt[s], 1);
    }
    __syncthreads();
    if (tid == 0) {
        int acc = 0;
        for (int q = 0; q < NQ_; ++q) { run[q] = acc; acc += cnt[q]; }
    }
    __syncthreads();
    for (int q = tid; q < NQ_; q += 1024) {
        ofs[q]  = run[q];
        degf[q] = (float)cnt[q];
    }
    if (tid == 0) ofs[NQ_] = E_;
    __syncthreads();
    for (int e = tid; e < E_; e += 1024) {
        int s = i64 ? ei[2 * e]        : ei[e];
        int t = i64 ? ei[2 * (E_ + e)] : ei[E_ + e];
        int p = atomicAdd(&run[s], 1);
        tgt_s[p] = t;
        a_s[p]   = attr[e];
    }
}

// ---------------------------------------------------------------------------
// Convert 12 weight matrices to bf16 [n][k] (native layout, no transpose)
// m = 6*k + {W1a, W1b, W2, n1a, n1b, n2}; also extract wl (e_w1[..][256]) fp32
// ---------------------------------------------------------------------------
__global__ __launch_bounds__(256) void k_prep(const float* __restrict__ e_w1,
                                              const float* __restrict__ e_w2,
                                              const float* __restrict__ n_w1,
                                              const float* __restrict__ n_w2,
                                              u16* __restrict__ wb,
                                              float* __restrict__ wl) {
    int m = blockIdx.x, k = m / 6, j = m % 6;
    const float* src; int ld, off;
    switch (j) {
        case 0: src = e_w1 + k * L_ * 257; ld = 257; off = 0;   break;
        case 1: src = e_w1 + k * L_ * 257; ld = 257; off = 128; break;
        case 2: src = e_w2 + k * L_ * L_;  ld = 128; off = 0;   break;
        case 3: src = n_w1 + k * L_ * 256; ld = 256; off = 0;   break;
        case 4: src = n_w1 + k * L_ * 256; ld = 256; off = 128; break;
        default:src = n_w2 + k * L_ * L_;  ld = 128; off = 0;   break;
    }
    u16* dst = wb + m * 16384;
    for (int idx = threadIdx.x; idx < 16384; idx += 256) {
        int n = idx >> 7, kk = idx & 127;
        dst[idx] = f2bf(src[n * ld + off + kk]);
    }
    if (j == 0) {
        for (int l = threadIdx.x; l < 128; l += 256)
            wl[k * 128 + l] = e_w1[k * L_ * 257 + l * 257 + 256];
    }
}

// ---------------------------------------------------------------------------
// ci = h@W1a^T + b1 (bias folded), cj = h@W1b^T     (bf16 MFMA, bf16 out)
// 64 rows/block, 4 waves, wave = one 16-row tile x 8 n-tiles
// ---------------------------------------------------------------------------
__global__ __launch_bounds__(256) void k_proj(const u16* __restrict__ hbf,
                                              const u16* __restrict__ W1a,
                                              const u16* __restrict__ W1b,
                                              const float* __restrict__ b1,
                                              u16* __restrict__ ci,
                                              u16* __restrict__ cj) {
    __shared__ u16 lt[4][16 * LDP];
    int lane = threadIdx.x & 63, w = threadIdx.x >> 6;
    int row0 = blockIdx.x * 64 + w * 16;
    floatx4 acc1[8] = {}, acc2[8] = {};
#pragma unroll
    for (int kb = 0; kb < 4; ++kb) {
        short8 a = gfrag(hbf, row0, kb, lane);
#pragma unroll
        for (int nt = 0; nt < 8; ++nt) {
            acc1[nt] = mfma16(a, gfrag(W1a, nt * 16, kb, lane), acc1[nt]);
            acc2[nt] = mfma16(a, gfrag(W1b, nt * 16, kb, lane), acc2[nt]);
        }
    }
    int col = lane & 15;
#pragma unroll
    for (int nt = 0; nt < 8; ++nt) {
        float bias = b1[nt * 16 + col];
#pragma unroll
        for (int r = 0; r < 4; ++r) acc1[nt][r] += bias;
    }
    tile_store(lt[w], acc1, lane);
    __syncthreads();
    tile_flush(lt[w], ci + (size_t)row0 * 128, lane);
    __syncthreads();
    tile_store(lt[w], acc2, lane);
    __syncthreads();
    tile_flush(lt[w], cj + (size_t)row0 * 128, lane);
}

// ---------------------------------------------------------------------------
// S[b,q,:] = sum_{e in seg(q)} relu( ci_b[b,q,:] + cj[b,tgt,:] + a_e*wl )
// one wave per (b,q); 2 bf16 cols per lane; b-major block order for L2 reuse
// ---------------------------------------------------------------------------
__global__ __launch_bounds__(256) void k_edge(const u16* __restrict__ ci,
                                              const u16* __restrict__ cj,
                                              const int* __restrict__ ofs,
                                              const int* __restrict__ tgt_s,
                                              const float* __restrict__ a_s,
                                              const float* __restrict__ wl,
                                              u16* __restrict__ S) {
    int lane = threadIdx.x & 63, w = threadIdx.x >> 6;
    int wq = blockIdx.x * 4 + w;
    int b = wq >> 10, q = wq & (NQ_ - 1);
    const u32* cjb = (const u32*)cj + (size_t)b * NQ_ * 64;
    u32 cv = ((const u32*)ci)[(size_t)wq * 64 + lane];
    float ci0 = bf2f((u16)(cv & 0xffff)), ci1 = bf2f((u16)(cv >> 16));
    float2 wl2 = ((const float2*)wl)[lane];
    int st = ofs[q], en = ofs[q + 1];
    float a0 = 0.0f, a1 = 0.0f;
    for (int idx = st; idx < en; ++idx) {
        int   t = tgt_s[idx];
        float a = a_s[idx];
        u32 jv = cjb[(size_t)t * 64 + lane];
        float v0 = ci0 + bf2f((u16)(jv & 0xffff)) + a * wl2.x;
        float v1 = ci1 + bf2f((u16)(jv >> 16))    + a * wl2.y;
        a0 += fmaxf(v0, 0.0f);
        a1 += fmaxf(v1, 0.0f);
    }
    ((u32*)S)[(size_t)wq * 64 + lane] = (u32)f2bf(a0) | ((u32)f2bf(a1) << 16);
}

// ---------------------------------------------------------------------------
// Fused node update (row-local):
//   m_agg = S@W2^T + deg*b2
//   x     = relu(h@n1a^T + m_agg@n1b^T + n_b1)
//   x     = LN(x)*g + b
//   h    += x@n2^T + n_b2          (fp32 master + bf16 mirror, in place)
// ---------------------------------------------------------------------------
__global__ __launch_bounds__(256) void k_node(const u16* __restrict__ S,
                                              u16* __restrict__ hbf,
                                              float* __restrict__ h,
                                              const u16* __restrict__ W2,
                                              const u16* __restrict__ n1a,
                                              const u16* __restrict__ n1b,
                                              const u16* __restrict__ n2,
                                              const float* __restrict__ e_b2,
                                              const float* __restrict__ degf,
                                              const float* __restrict__ n_b1,
                                              const float* __restrict__ g,
                                              const float* __restrict__ bb,
                                              const float* __restrict__ n_b2) {
    __shared__ u16 lt[4][16 * LDP];
    int lane = threadIdx.x & 63, w = threadIdx.x >> 6;
    int row0 = blockIdx.x * 64 + w * 16;
    int col = lane & 15, qd = lane >> 4;

    // ---- phase 1: m_agg = S@W2^T + deg*b2
    floatx4 acc[8] = {};
#pragma unroll
    for (int kb = 0; kb < 4; ++kb) {
        short8 a = gfrag(S, row0, kb, lane);
#pragma unroll
        for (int nt = 0; nt < 8; ++nt)
            acc[nt] = mfma16(a, gfrag(W2, nt * 16, kb, lane), acc[nt]);
    }
#pragma unroll
    for (int nt = 0; nt < 8; ++nt) {
        float b2v = e_b2[nt * 16 + col];
#pragma unroll
        for (int r = 0; r < 4; ++r) {
            int row = row0 + qd * 4 + r;
            acc[nt][r] += degf[row & (NQ_ - 1)] * b2v;
        }
    }
    tile_store(lt[w], acc, lane);     // m_agg tile, bf16, A-layout-readable
    __syncthreads();

    // ---- phase 2: x = relu(h@n1a + m_agg@n1b + n_b1)
    floatx4 xa[8] = {};
#pragma unroll
    for (int kb = 0; kb < 4; ++kb) {
        short8 ah = gfrag(hbf, row0, kb, lane);
        short8 am = lfrag(lt[w], kb, lane);
#pragma unroll
        for (int nt = 0; nt < 8; ++nt) {
            xa[nt] = mfma16(ah, gfrag(n1a, nt * 16, kb, lane), xa[nt]);
            xa[nt] = mfma16(am, gfrag(n1b, nt * 16, kb, lane), xa[nt]);
        }
    }
#pragma unroll
    for (int nt = 0; nt < 8; ++nt) {
        float bv = n_b1[nt * 16 + col];
#pragma unroll
        for (int r = 0; r < 4; ++r) xa[nt][r] = fmaxf(xa[nt][r] + bv, 0.0f);
    }

    // ---- phase 3: LayerNorm per row (row = qd*4+r; cols spread over 16 lanes x 8 nt)
#pragma unroll
    for (int r = 0; r < 4; ++r) {
        float s = 0.0f, s2 = 0.0f;
#pragma unroll
        for (int nt = 0; nt < 8; ++nt) { float v = xa[nt][r]; s += v; s2 += v * v; }
#pragma unroll
        for (int o = 1; o < 16; o <<= 1) {
            s  += __shfl_xor(s,  o, 64);
            s2 += __shfl_xor(s2, o, 64);
        }
        float mu = s * (1.0f / 128.0f);
        float var = s2 * (1.0f / 128.0f) - mu * mu;
        float rs = rsqrtf(var + 1e-5f);
#pragma unroll
        for (int nt = 0; nt < 8; ++nt) {
            int cg = nt * 16 + col;
            xa[nt][r] = (xa[nt][r] - mu) * rs * g[cg] + bb[cg];
        }
    }
    __syncthreads();                  // lt (m_agg) no longer needed
    tile_store(lt[w], xa, lane);      // x tile bf16
    __syncthreads();

    // ---- phase 4: h += x@n2^T + n_b2
    floatx4 ha[8] = {};
#pragma unroll
    for (int kb = 0; kb < 4; ++kb) {
        short8 ax = lfrag(lt[w], kb, lane);
#pragma unroll
        for (int nt = 0; nt < 8; ++nt)
            ha[nt] = mfma16(ax, gfrag(n2, nt * 16, kb, lane), ha[nt]);
    }
#pragma unroll
    for (int nt = 0; nt < 8; ++nt) {
        int cg = nt * 16 + col;
        float b2v = n_b2[cg];
#pragma unroll
        for (int r = 0; r < 4; ++r) {
            size_t off = (size_t)(row0 + qd * 4 + r) * 128 + cg;
            float hv = h[off] + ha[nt][r] + b2v;
            h[off] = hv;
            ha[nt][r] = hv;
        }
    }
    __syncthreads();                  // lt (x) no longer needed
    tile_store(lt[w], ha, lane);
    __syncthreads();
    tile_flush(lt[w], hbf + (size_t)row0 * 128, lane);   // bf16 mirror in place
}

// ---------------------------------------------------------------------------
// final mean over q
// ---------------------------------------------------------------------------
__global__ __launch_bounds__(128) void k_partial(const float* __restrict__ h,
                                                 float* __restrict__ partial) {
    int c = blockIdx.x;          // 512 = 64 b * 8 chunks
    int b = c >> 3, ch = c & 7;
    float acc = 0.0f;
    int q0 = ch * 128;
    for (int q = q0; q < q0 + 128; ++q)
        acc += h[(size_t)(b * NQ_ + q) * L_ + threadIdx.x];
    partial[c * 128 + threadIdx.x] = acc;
}

__global__ __launch_bounds__(256) void k_final(const float* __restrict__ partial,
                                               float* __restrict__ out) {
    int i = blockIdx.x * 256 + threadIdx.x;    // 8192
    int b = i >> 7, l = i & 127;
    float s = 0.0f;
#pragma unroll
    for (int c = 0; c < 8; ++c) s += partial[(b * 8 + c) * 128 + l];
    out[i] = s * (1.0f / 1024.0f);
}

// ---------------------------------------------------------------------------
extern "C" void kernel_launch(void* const* d_in, const int* in_sizes, int n_in,
                              void* d_out, int out_size, void* d_ws, size_t ws_size,
                              hipStream_t stream) {
    const float* z0    = (const float*)d_in[0];
    const int*   ei    = (const int*)d_in[1];
    const float* attr  = (const float*)d_in[2];
    const float* e_w1  = (const float*)d_in[4];
    const float* e_b1  = (const float*)d_in[5];
    const float* e_w2  = (const float*)d_in[6];
    const float* e_b2  = (const float*)d_in[7];
    const float* n_w1  = (const float*)d_in[8];
    const float* n_b1  = (const float*)d_in[9];
    const float* ln_g  = (const float*)d_in[10];
    const float* ln_b  = (const float*)d_in[11];
    const float* n_w2  = (const float*)d_in[12];
    const float* n_b2  = (const float*)d_in[13];
    float* out = (float*)d_out;

    const size_t H = (size_t)M_ * L_;            // 8388608
    float* f     = (float*)d_ws;
    float* h     = f;                            // H floats
    float* part  = f + H;                        // 65536
    float* degf  = part + 65536;                 // 1024
    float* a_s   = degf + 1024;                  // 8192
    float* wl    = a_s + 8192;                   // 256
    int*   ofs   = (int*)(wl + 256);             // 1025 (pad 1056)
    int*   tgt_s = ofs + 1056;                   // 8192
    u16*   hbf   = (u16*)(tgt_s + 8192);         // H shorts each:
    u16*   ci    = hbf + H;
    u16*   cj    = ci + H;
    u16*   S     = cj + H;
    u16*   wb    = S + H;                        // 12*16384 shorts

    k_init_h<<<8192, 256, 0, stream>>>(h, hbf, z0);
    k_csr<<<1, 1024, 0, stream>>>(ei, attr, ofs, tgt_s, a_s, degf);
    k_prep<<<12, 256, 0, stream>>>(e_w1, e_w2, n_w1, n_w2, wb, wl);

    for (int k = 0; k < 2; ++k) {
        const u16* wtk = wb + k * 6 * 16384;
        k_proj<<<1024, 256, 0, stream>>>(hbf, wtk, wtk + 16384, e_b1 + k * L_, ci, cj);
        k_edge<<<16384, 256, 0, stream>>>(ci, cj, ofs, tgt_s, a_s, wl + k * L_, S);
        k_node<<<1024, 256, 0, stream>>>(S, hbf, h,
                                         wtk + 2 * 16384, wtk + 3 * 16384,
                                         wtk + 4 * 16384, wtk + 5 * 16384,
                                         e_b2 + k * L_, degf, n_b1 + k * L_,
                                         ln_g + k * L_, ln_b + k * L_, n_b2 + k * L_);
    }
    k_partial<<<512, 128, 0, stream>>>(h, part);
    k_final<<<32, 256, 0, stream>>>(part, out);
}

// Round 3
// 366.302 us; speedup vs baseline: 1.7745x; 1.2881x over previous
//
#include <hip/hip_runtime.h>

#define B_   64
#define NQ_  1024
#define L_   128
#define E_   8192
#define M_   (B_*NQ_)   // 65536 rows
#define LDP  136        // padded LDS row stride (shorts)

typedef unsigned short u16;
typedef unsigned int   u32;
typedef __attribute__((ext_vector_type(8))) short short8;   // 8 bf16
typedef __attribute__((ext_vector_type(4))) float floatx4;  // MFMA C/D

#define WB() __builtin_amdgcn_wave_barrier()   // compiler sched fence; DS ops are in-order per wave

__device__ __forceinline__ u16 f2bf(float f) {              // RNE fp32->bf16
    union { float f; u32 u; } v; v.f = f;
    return (u16)((v.u + 0x7fffu + ((v.u >> 16) & 1u)) >> 16);
}
__device__ __forceinline__ float bf2f(u16 u) {
    union { u32 u; float f; } v; v.u = ((u32)u) << 16;
    return v.f;
}
__device__ __forceinline__ floatx4 mfma16(short8 a, short8 b, floatx4 c) {
    return __builtin_amdgcn_mfma_f32_16x16x32_bf16(a, b, c, 0, 0, 0);
}
// A/B fragment from global row-major bf16 [.][128]
__device__ __forceinline__ short8 gfrag(const u16* base, int r0, int kb, int lane) {
    return *(const short8*)(base + (size_t)(r0 + (lane & 15)) * 128 + kb * 32 + (lane >> 4) * 8);
}
// fragment from fp32 row-major with leading dim ld, converted to bf16
__device__ __forceinline__ short8 frag_cvt(const float* base, int r0, int ld, int kb, int lane) {
    const float* p = base + (size_t)(r0 + (lane & 15)) * ld + kb * 32 + (lane >> 4) * 8;
    short8 s;
#pragma unroll
    for (int j = 0; j < 8; ++j) s[j] = (short)f2bf(p[j]);
    return s;
}
// broadcast fragment: all 16 rows identical (fp32 source row)
__device__ __forceinline__ short8 frag_bcast(const float* rowp, int kb, int lane) {
    const float* p = rowp + kb * 32 + (lane >> 4) * 8;
    short8 s;
#pragma unroll
    for (int j = 0; j < 8; ++j) s[j] = (short)f2bf(p[j]);
    return s;
}
__device__ __forceinline__ short8 lfrag(const u16* t, int kb, int lane) {
    return *(const short8*)(t + (lane & 15) * LDP + kb * 32 + (lane >> 4) * 8);
}
// C-layout frags (8 n-tiles x 4 regs) -> bf16 LDS tile [16][LDP]
__device__ __forceinline__ void tile_store(u16* t, const floatx4* acc, int lane) {
    int col = lane & 15, qd = lane >> 4;
#pragma unroll
    for (int nt = 0; nt < 8; ++nt)
#pragma unroll
        for (int r = 0; r < 4; ++r)
            t[(qd * 4 + r) * LDP + nt * 16 + col] = f2bf(acc[nt][r]);
}
// LDS tile -> global rows (coalesced 16B stores)
__device__ __forceinline__ void tile_flush(const u16* t, u16* g, int lane) {
#pragma unroll
    for (int it = 0; it < 4; ++it) {
        int chunk = it * 64 + lane, row = chunk >> 4, c8 = chunk & 15;
        *(uint4*)(g + (size_t)row * 128 + c8 * 8) = *(const uint4*)(t + row * LDP + c8 * 8);
    }
}

// ---------------------------------------------------------------------------
// Setup dispatch: block 0 = CSR build; blocks 1..12 = weight bf16 prep;
// block 13 = round-0 projection (ci0/cj0, only 64 rows each!)
// ---------------------------------------------------------------------------
__global__ __launch_bounds__(1024) void k_setup(const int* __restrict__ ei,
                                                const float* __restrict__ attr,
                                                const float* __restrict__ z0,
                                                const float* __restrict__ e_w1,
                                                const float* __restrict__ e_b1,
                                                const float* __restrict__ e_w2,
                                                const float* __restrict__ n_w1,
                                                const float* __restrict__ n_w2,
                                                int* __restrict__ ofs,
                                                int* __restrict__ tgt_s,
                                                float* __restrict__ a_s,
                                                float* __restrict__ degf,
                                                u16* __restrict__ wb,
                                                float* __restrict__ wl,
                                                u16* __restrict__ ci0,
                                                u16* __restrict__ cj0) {
    __shared__ int cnt[NQ_];
    __shared__ int wbase[17];
    __shared__ int s_i64;
    __shared__ u16 lt[4][16 * LDP];
    int tid = threadIdx.x, blk = blockIdx.x;

    if (blk == 0) {                       // ---------------- CSR
        if (tid == 0) s_i64 = 1;
        cnt[tid] = 0;
        __syncthreads();
        if (tid < 100) {
            if (ei[2 * tid + 1] != 0) atomicAnd(&s_i64, 0);
        }
        __syncthreads();
        int i64 = s_i64;
        for (int e = tid; e < E_; e += 1024) {
            int s = i64 ? ei[2 * e] : ei[e];
            atomicAdd(&cnt[s], 1);
        }
        __syncthreads();
        int lane = tid & 63, wv = tid >> 6;
        int v = cnt[tid], inc = v;
#pragma unroll
        for (int o = 1; o < 64; o <<= 1) {
            int t = __shfl_up(inc, o, 64);
            if (lane >= o) inc += t;
        }
        if (lane == 63) wbase[wv + 1] = inc;
        if (tid == 0) wbase[0] = 0;
        __syncthreads();
        if (tid == 0)
            for (int i = 1; i <= 16; ++i) wbase[i] += wbase[i - 1];
        __syncthreads();
        int ex = wbase[wv] + inc - v;     // exclusive prefix
        ofs[tid]  = ex;
        degf[tid] = (float)v;
        if (tid == 0) ofs[NQ_] = E_;
        cnt[tid] = ex;                    // reuse as running cursor
        __syncthreads();
        for (int e = tid; e < E_; e += 1024) {
            int s = i64 ? ei[2 * e]        : ei[e];
            int t = i64 ? ei[2 * (E_ + e)] : ei[E_ + e];
            int p = atomicAdd(&cnt[s], 1);
            tgt_s[p] = t;
            a_s[p]   = attr[e];
        }
    } else if (blk <= 12) {               // ---------------- weight prep
        int m = blk - 1, k = m / 6, j = m % 6;
        const float* src; int ld, off;
        switch (j) {
            case 0: src = e_w1 + k * L_ * 257; ld = 257; off = 0;   break;
            case 1: src = e_w1 + k * L_ * 257; ld = 257; off = 128; break;
            case 2: src = e_w2 + k * L_ * L_;  ld = 128; off = 0;   break;
            case 3: src = n_w1 + k * L_ * 256; ld = 256; off = 0;   break;
            case 4: src = n_w1 + k * L_ * 256; ld = 256; off = 128; break;
            default:src = n_w2 + k * L_ * L_;  ld = 128; off = 0;   break;
        }
        u16* dst = wb + m * 16384;
        for (int idx = tid; idx < 16384; idx += 1024) {
            int n = idx >> 7, kk = idx & 127;
            dst[idx] = f2bf(src[n * ld + off + kk]);
        }
        if (j == 0) {
            for (int l = tid; l < 128; l += 1024)
                wl[k * 128 + l] = e_w1[k * L_ * 257 + l * 257 + 256];
        }
    } else {                              // ---------------- round-0 proj (64 rows)
        int lane = tid & 63, wv = tid >> 6;
        if (wv < 4) {
            int r0 = wv * 16;
            floatx4 a1[8] = {}, a2[8] = {};
#pragma unroll
            for (int kb = 0; kb < 4; ++kb) {
                short8 a = frag_cvt(z0, r0, 128, kb, lane);
#pragma unroll
                for (int nt = 0; nt < 8; ++nt) {
                    a1[nt] = mfma16(a, frag_cvt(e_w1,       nt * 16, 257, kb, lane), a1[nt]);
                    a2[nt] = mfma16(a, frag_cvt(e_w1 + 128, nt * 16, 257, kb, lane), a2[nt]);
                }
            }
            int col = lane & 15;
#pragma unroll
            for (int nt = 0; nt < 8; ++nt) {
                float bv = e_b1[nt * 16 + col];
#pragma unroll
                for (int r = 0; r < 4; ++r) a1[nt][r] += bv;
            }
            tile_store(lt[wv], a1, lane); WB();
            tile_flush(lt[wv], ci0 + (size_t)r0 * 128, lane); WB();
            tile_store(lt[wv], a2, lane); WB();
            tile_flush(lt[wv], cj0 + (size_t)r0 * 128, lane);
        }
    }
}

// ---------------------------------------------------------------------------
// Edge gather: S[b,q,:] = sum_e relu(ci(b,q) + cj(b,tgt_e) + a_e*wl)
// strides in u32 units; round 0 uses qs=ts=0 (broadcast rows)
// ---------------------------------------------------------------------------
__global__ __launch_bounds__(256) void k_edge(const u16* __restrict__ ci,
                                              const u16* __restrict__ cj,
                                              size_t ci_bs, size_t ci_qs,
                                              size_t cj_bs, size_t cj_ts,
                                              const int* __restrict__ ofs,
                                              const int* __restrict__ tgt_s,
                                              const float* __restrict__ a_s,
                                              const float* __restrict__ wl,
                                              u16* __restrict__ S) {
    int lane = threadIdx.x & 63, w = threadIdx.x >> 6;
    int wq = blockIdx.x * 4 + w;
    int b = wq >> 10, q = wq & (NQ_ - 1);
    const u32* cip = (const u32*)ci + b * ci_bs + q * ci_qs;
    const u32* cjp = (const u32*)cj + b * cj_bs;
    u32 cv = cip[lane];
    float ci0 = bf2f((u16)(cv & 0xffff)), ci1 = bf2f((u16)(cv >> 16));
    float2 wl2 = ((const float2*)wl)[lane];
    int st = ofs[q], en = ofs[q + 1];
    float a0 = 0.0f, a1 = 0.0f;
    for (int idx = st; idx < en; ++idx) {
        int   t = tgt_s[idx];
        float a = a_s[idx];
        u32 jv = cjp[(size_t)t * cj_ts + lane];
        float v0 = ci0 + bf2f((u16)(jv & 0xffff)) + a * wl2.x;
        float v1 = ci1 + bf2f((u16)(jv >> 16))    + a * wl2.y;
        a0 += fmaxf(v0, 0.0f);
        a1 += fmaxf(v1, 0.0f);
    }
    ((u32*)S)[(size_t)wq * 64 + lane] = (u32)f2bf(a0) | ((u32)f2bf(a1) << 16);
}

// ---------------------------------------------------------------------------
// Fused node update.
// R0=true : h_prev = z0 broadcast; writes h (fp32); emits ci/cj for round 1.
// R0=false: h_prev = h (fp32); no h write; fused mean -> atomicAdd into out.
// ---------------------------------------------------------------------------
template <bool R0>
__global__ __launch_bounds__(256) void k_node(const u16* __restrict__ S,
                                              float* __restrict__ h,
                                              const float* __restrict__ z0,
                                              const u16* __restrict__ W2,
                                              const u16* __restrict__ n1a,
                                              const u16* __restrict__ n1b,
                                              const u16* __restrict__ n2,
                                              const float* __restrict__ e_b2,
                                              const float* __restrict__ degf,
                                              const float* __restrict__ n_b1,
                                              const float* __restrict__ g,
                                              const float* __restrict__ bb,
                                              const float* __restrict__ n_b2,
                                              const u16* __restrict__ W1a2,
                                              const u16* __restrict__ W1b2,
                                              const float* __restrict__ b1_2,
                                              u16* __restrict__ ci,
                                              u16* __restrict__ cj,
                                              float* __restrict__ out) {
    __shared__ u16 lt[4][16 * LDP];
    __shared__ float rsum[4][128];
    int lane = threadIdx.x & 63, w = threadIdx.x >> 6;
    int row0 = blockIdx.x * 64 + w * 16;
    int b = blockIdx.x >> 4;              // 16 blocks per batch
    int col = lane & 15, qd = lane >> 4;

    // ---- phase 1: m_agg = S@W2^T + deg*b2  -> LDS tile
    floatx4 acc[8] = {};
#pragma unroll
    for (int kb = 0; kb < 4; ++kb) {
        short8 a = gfrag(S, row0, kb, lane);
#pragma unroll
        for (int nt = 0; nt < 8; ++nt)
            acc[nt] = mfma16(a, gfrag(W2, nt * 16, kb, lane), acc[nt]);
    }
#pragma unroll
    for (int nt = 0; nt < 8; ++nt) {
        float b2v = e_b2[nt * 16 + col];
#pragma unroll
        for (int r = 0; r < 4; ++r)
            acc[nt][r] += degf[(row0 + qd * 4 + r) & (NQ_ - 1)] * b2v;
    }
    tile_store(lt[w], acc, lane);
    WB();

    // ---- phase 2: x = relu(h_prev@n1a + m_agg@n1b + n_b1)
    floatx4 xa[8] = {};
#pragma unroll
    for (int kb = 0; kb < 4; ++kb) {
        short8 ah = R0 ? frag_bcast(z0 + b * 128, kb, lane)
                       : frag_cvt(h, row0, 128, kb, lane);
        short8 am = lfrag(lt[w], kb, lane);
#pragma unroll
        for (int nt = 0; nt < 8; ++nt) {
            xa[nt] = mfma16(ah, gfrag(n1a, nt * 16, kb, lane), xa[nt]);
            xa[nt] = mfma16(am, gfrag(n1b, nt * 16, kb, lane), xa[nt]);
        }
    }
#pragma unroll
    for (int nt = 0; nt < 8; ++nt) {
        float bv = n_b1[nt * 16 + col];
#pragma unroll
        for (int r = 0; r < 4; ++r) xa[nt][r] = fmaxf(xa[nt][r] + bv, 0.0f);
    }

    // ---- phase 3: LayerNorm per row
#pragma unroll
    for (int r = 0; r < 4; ++r) {
        float s = 0.0f, s2 = 0.0f;
#pragma unroll
        for (int nt = 0; nt < 8; ++nt) { float v = xa[nt][r]; s += v; s2 += v * v; }
#pragma unroll
        for (int o = 1; o < 16; o <<= 1) {
            s  += __shfl_xor(s,  o, 64);
            s2 += __shfl_xor(s2, o, 64);
        }
        float mu  = s * (1.0f / 128.0f);
        float var = s2 * (1.0f / 128.0f) - mu * mu;
        float rs  = rsqrtf(var + 1e-5f);
#pragma unroll
        for (int nt = 0; nt < 8; ++nt) {
            int cg = nt * 16 + col;
            xa[nt][r] = (xa[nt][r] - mu) * rs * g[cg] + bb[cg];
        }
    }
    WB();
    tile_store(lt[w], xa, lane);          // x tile (m_agg dead)
    WB();

    // ---- phase 4: hv = h_prev + x@n2^T + n_b2
    floatx4 ha[8] = {};
#pragma unroll
    for (int kb = 0; kb < 4; ++kb) {
        short8 ax = lfrag(lt[w], kb, lane);
#pragma unroll
        for (int nt = 0; nt < 8; ++nt)
            ha[nt] = mfma16(ax, gfrag(n2, nt * 16, kb, lane), ha[nt]);
    }
    if (R0) {
#pragma unroll
        for (int nt = 0; nt < 8; ++nt) {
            int cg = nt * 16 + col;
            float hp = z0[b * 128 + cg] + n_b2[cg];
#pragma unroll
            for (int r = 0; r < 4; ++r) {
                float hv = hp + ha[nt][r];
                h[(size_t)(row0 + qd * 4 + r) * 128 + cg] = hv;
                ha[nt][r] = hv;
            }
        }
        WB();
        tile_store(lt[w], ha, lane);      // bf16 h tile for fused proj
        WB();
        // ---- phases 5/6: ci = hv@W1a2^T + b1_2, cj = hv@W1b2^T
        floatx4 pc[8] = {}, pd[8] = {};
#pragma unroll
        for (int kb = 0; kb < 4; ++kb) {
            short8 ax = lfrag(lt[w], kb, lane);
#pragma unroll
            for (int nt = 0; nt < 8; ++nt) {
                pc[nt] = mfma16(ax, gfrag(W1a2, nt * 16, kb, lane), pc[nt]);
                pd[nt] = mfma16(ax, gfrag(W1b2, nt * 16, kb, lane), pd[nt]);
            }
        }
#pragma unroll
        for (int nt = 0; nt < 8; ++nt) {
            float bv = b1_2[nt * 16 + col];
#pragma unroll
            for (int r = 0; r < 4; ++r) pc[nt][r] += bv;
        }
        WB();
        tile_store(lt[w], pc, lane); WB();
        tile_flush(lt[w], ci + (size_t)row0 * 128, lane); WB();
        tile_store(lt[w], pd, lane); WB();
        tile_flush(lt[w], cj + (size_t)row0 * 128, lane);
    } else {
        // residual + fused mean over q
        float s[8];
#pragma unroll
        for (int nt = 0; nt < 8; ++nt) {
            int cg = nt * 16 + col;
            float b2v = n_b2[cg];
            float acc4 = 0.0f;
#pragma unroll
            for (int r = 0; r < 4; ++r) {
                float hv = h[(size_t)(row0 + qd * 4 + r) * 128 + cg] + ha[nt][r] + b2v;
                acc4 += hv;
            }
            s[nt] = acc4;
        }
#pragma unroll
        for (int nt = 0; nt < 8; ++nt) {
            s[nt] += __shfl_xor(s[nt], 16, 64);
            s[nt] += __shfl_xor(s[nt], 32, 64);
        }
        if (lane < 16) {
#pragma unroll
            for (int nt = 0; nt < 8; ++nt) rsum[w][nt * 16 + lane] = s[nt];
        }
        __syncthreads();
        if (threadIdx.x < 128) {
            float v = rsum[0][threadIdx.x] + rsum[1][threadIdx.x] +
                      rsum[2][threadIdx.x] + rsum[3][threadIdx.x];
            atomicAdd(out + b * 128 + threadIdx.x, v * (1.0f / 1024.0f));
        }
    }
}

// ---------------------------------------------------------------------------
extern "C" void kernel_launch(void* const* d_in, const int* in_sizes, int n_in,
                              void* d_out, int out_size, void* d_ws, size_t ws_size,
                              hipStream_t stream) {
    const float* z0    = (const float*)d_in[0];
    const int*   ei    = (const int*)d_in[1];
    const float* attr  = (const float*)d_in[2];
    const float* e_w1  = (const float*)d_in[4];
    const float* e_b1  = (const float*)d_in[5];
    const float* e_w2  = (const float*)d_in[6];
    const float* e_b2  = (const float*)d_in[7];
    const float* n_w1  = (const float*)d_in[8];
    const float* n_b1  = (const float*)d_in[9];
    const float* ln_g  = (const float*)d_in[10];
    const float* ln_b  = (const float*)d_in[11];
    const float* n_w2  = (const float*)d_in[12];
    const float* n_b2  = (const float*)d_in[13];
    float* out = (float*)d_out;

    const size_t H = (size_t)M_ * L_;            // 8388608
    float* f     = (float*)d_ws;
    float* h     = f;                            // H floats
    float* wl    = f + H;                        // 256
    float* degf  = wl + 256;                     // 1024
    float* a_s   = degf + 1024;                  // 8192
    int*   ofs   = (int*)(a_s + 8192);           // 1025 (pad 1056)
    int*   tgt_s = ofs + 1056;                   // 8192
    u16*   ci1   = (u16*)(tgt_s + 8192);         // H shorts each:
    u16*   cj1   = ci1 + H;
    u16*   S     = cj1 + H;
    u16*   wb    = S + H;                        // 12*16384
    u16*   ci0   = wb + 12 * 16384;              // 8192
    u16*   cj0   = ci0 + 8192;                   // 8192

    hipMemsetAsync(out, 0, 8192 * sizeof(float), stream);

    k_setup<<<14, 1024, 0, stream>>>(ei, attr, z0, e_w1, e_b1, e_w2, n_w1, n_w2,
                                     ofs, tgt_s, a_s, degf, wb, wl, ci0, cj0);

    // round 0: edge gather on broadcast ci0/cj0 (q/t strides = 0)
    k_edge<<<16384, 256, 0, stream>>>(ci0, cj0, 64, 0, 64, 0,
                                      ofs, tgt_s, a_s, wl, S);
    // node0: h = z0 + f(S); also emits ci1/cj1 for round 1
    k_node<true><<<1024, 256, 0, stream>>>(S, h, z0,
                                           wb + 2 * 16384, wb + 3 * 16384,
                                           wb + 4 * 16384, wb + 5 * 16384,
                                           e_b2, degf, n_b1, ln_g, ln_b, n_b2,
                                           wb + 6 * 16384, wb + 7 * 16384,
                                           e_b1 + L_, ci1, cj1, nullptr);
    // round 1: full-stride edge gather
    k_edge<<<16384, 256, 0, stream>>>(ci1, cj1, (size_t)NQ_ * 64, 64,
                                      (size_t)NQ_ * 64, 64,
                                      ofs, tgt_s, a_s, wl + L_, S);
    // node1: residual + fused mean into out
    k_node<false><<<1024, 256, 0, stream>>>(S, h, z0,
                                            wb + 8 * 16384, wb + 9 * 16384,
                                            wb + 10 * 16384, wb + 11 * 16384,
                                            e_b2 + L_, degf, n_b1 + L_,
                                            ln_g + L_, ln_b + L_, n_b2 + L_,
                                            nullptr, nullptr, nullptr, nullptr,
                                            nullptr, out);
}

// Round 4
// 197.087 us; speedup vs baseline: 3.2981x; 1.8586x over previous
//
#include <hip/hip_runtime.h>

#define B_   64
#define NQ_  1024
#define L_   128
#define E_   8192
#define M_   (B_*NQ_)
#define LDP  136        // padded LDS row stride (shorts): 272 B, 16B-aligned, 2-way conflicts only

typedef unsigned short u16;
typedef unsigned int   u32;
typedef __attribute__((ext_vector_type(8))) short short8;   // 8 bf16
typedef __attribute__((ext_vector_type(4))) float floatx4;  // MFMA C/D

#define WVB() __builtin_amdgcn_wave_barrier()

__device__ __forceinline__ u16 f2bf(float f) {              // RNE fp32->bf16
    union { float f; u32 u; } v; v.f = f;
    return (u16)((v.u + 0x7fffu + ((v.u >> 16) & 1u)) >> 16);
}
__device__ __forceinline__ float bf2f(u16 u) {
    union { u32 u; float f; } v; v.u = ((u32)u) << 16;
    return v.f;
}
__device__ __forceinline__ floatx4 mfma16(short8 a, short8 b, floatx4 c) {
    return __builtin_amdgcn_mfma_f32_16x16x32_bf16(a, b, c, 0, 0, 0);
}
// A/B fragment from global row-major bf16 [.][128]
__device__ __forceinline__ short8 gfrag(const u16* base, int r0, int kb, int lane) {
    return *(const short8*)(base + (size_t)(r0 + (lane & 15)) * 128 + kb * 32 + (lane >> 4) * 8);
}
// fragment from padded LDS (row stride LDP)
__device__ __forceinline__ short8 sfrag(const u16* t, int r0, int kb, int lane) {
    return *(const short8*)(t + (r0 + (lane & 15)) * LDP + kb * 32 + (lane >> 4) * 8);
}
// fragment from fp32 row-major with leading dim ld, converted to bf16
__device__ __forceinline__ short8 frag_cvt(const float* base, int r0, int ld, int kb, int lane) {
    const float* p = base + (size_t)(r0 + (lane & 15)) * ld + kb * 32 + (lane >> 4) * 8;
    short8 s;
#pragma unroll
    for (int j = 0; j < 8; ++j) s[j] = (short)f2bf(p[j]);
    return s;
}
// C-layout frags (8 n-tiles x 4 regs) -> bf16 LDS tile [16][LDP]
__device__ __forceinline__ void tile_store(u16* t, const floatx4* acc, int lane) {
    int col = lane & 15, qd = lane >> 4;
#pragma unroll
    for (int nt = 0; nt < 8; ++nt)
#pragma unroll
        for (int r = 0; r < 4; ++r)
            t[(qd * 4 + r) * LDP + nt * 16 + col] = f2bf(acc[nt][r]);
}
// LDS tile -> global rows (coalesced 16B stores)
__device__ __forceinline__ void tile_flush(const u16* t, u16* g, int lane) {
#pragma unroll
    for (int it = 0; it < 4; ++it) {
        int chunk = it * 64 + lane, row = chunk >> 4, c8 = chunk & 15;
        *(uint4*)(g + (size_t)row * 128 + c8 * 8) = *(const uint4*)(t + row * LDP + c8 * 8);
    }
}
// stage a 128x128 bf16 weight (row-major in global) into padded LDS
__device__ __forceinline__ void stage_w(u16* wbuf, const u16* g, int tid) {
    const uint4* g4 = (const uint4*)g;
#pragma unroll
    for (int i = 0; i < 8; ++i) {
        int idx = tid + i * 256, row = idx >> 4, c8 = idx & 15;
        *(uint4*)&wbuf[row * LDP + c8 * 8] = g4[idx];
    }
}

// ---------------------------------------------------------------------------
// Setup: blk0 CSR; blk1-3 direct bf16 weight cvt; blk4-7 precomputed-product
// GEMMs (Wc0,Wc1,Wd,We); blk8-10 z0 row tables; blk11 ci0/cj0; blk12 vb2+wl
// wb slots: 0=Wc0 1=n2_0 2=Wd 3=We 4=n1a_1 5=Wc1 6=n2_1
// ---------------------------------------------------------------------------
__global__ __launch_bounds__(256) void k_setup(const int* __restrict__ ei,
                                               const float* __restrict__ attr,
                                               const float* __restrict__ z0,
                                               const float* __restrict__ e_w1,
                                               const float* __restrict__ e_b1,
                                               const float* __restrict__ e_w2,
                                               const float* __restrict__ e_b2,
                                               const float* __restrict__ n_w1,
                                               const float* __restrict__ n_b1,
                                               const float* __restrict__ n_w2,
                                               const float* __restrict__ n_b2,
                                               int* __restrict__ ofs,
                                               int* __restrict__ tgt_s,
                                               float* __restrict__ a_s,
                                               float* __restrict__ degf,
                                               u16* __restrict__ wb,
                                               float* __restrict__ wl,
                                               float* __restrict__ vb2,
                                               float* __restrict__ rx,
                                               float* __restrict__ rci,
                                               float* __restrict__ rcj,
                                               u16* __restrict__ ci0,
                                               u16* __restrict__ cj0) {
    __shared__ __align__(16) char smem[52608];
    int tid = threadIdx.x, blk = blockIdx.x;
    int lane = tid & 63, w = tid >> 6, col = lane & 15, qd = lane >> 4;

    if (blk == 0) {                           // -------- CSR build
        int* cnt  = (int*)smem;               // 1024
        int* wsum = cnt + 1024;               // 4
        int* flag = wsum + 8;
#pragma unroll
        for (int i = 0; i < 4; ++i) cnt[tid + i * 256] = 0;
        if (tid == 0) *flag = 1;
        __syncthreads();
        if (tid < 100 && ei[2 * tid + 1] != 0) atomicAnd(flag, 0);
        __syncthreads();
        int i64 = *flag;
        for (int e = tid; e < E_; e += 256) {
            int s = i64 ? ei[2 * e] : ei[e];
            atomicAdd(&cnt[s], 1);
        }
        __syncthreads();
        int q0 = tid * 4;
        int c0 = cnt[q0], c1 = cnt[q0 + 1], c2 = cnt[q0 + 2], c3 = cnt[q0 + 3];
        int tsum = c0 + c1 + c2 + c3, incl = tsum;
#pragma unroll
        for (int o = 1; o < 64; o <<= 1) {
            int t = __shfl_up(incl, o, 64);
            if (lane >= o) incl += t;
        }
        if (lane == 63) wsum[w] = incl;
        __syncthreads();
        int wo = 0;
        for (int i = 0; i < w; ++i) wo += wsum[i];
        int base = wo + incl - tsum;
        ofs[q0] = base; ofs[q0 + 1] = base + c0;
        ofs[q0 + 2] = base + c0 + c1; ofs[q0 + 3] = base + c0 + c1 + c2;
        degf[q0] = (float)c0; degf[q0 + 1] = (float)c1;
        degf[q0 + 2] = (float)c2; degf[q0 + 3] = (float)c3;
        if (tid == 0) ofs[NQ_] = E_;
        __syncthreads();
        cnt[q0] = base; cnt[q0 + 1] = base + c0;
        cnt[q0 + 2] = base + c0 + c1; cnt[q0 + 3] = base + c0 + c1 + c2;
        __syncthreads();
        for (int e = tid; e < E_; e += 256) {
            int s = i64 ? ei[2 * e]        : ei[e];
            int t = i64 ? ei[2 * (E_ + e)] : ei[E_ + e];
            int p = atomicAdd(&cnt[s], 1);
            tgt_s[p] = t;
            a_s[p]   = attr[e];
        }
    } else if (blk <= 3) {                    // -------- direct bf16 cvt
        const float* src; int ld, off; u16* dst;
        if (blk == 1)      { src = n_w2;         ld = 128; off = 0; dst = wb + 1 * 16384; }
        else if (blk == 2) { src = n_w2 + 16384; ld = 128; off = 0; dst = wb + 6 * 16384; }
        else               { src = n_w1 + 32768; ld = 256; off = 0; dst = wb + 4 * 16384; }
        for (int idx = tid; idx < 16384; idx += 256) {
            int n = idx >> 7, kk = idx & 127;
            dst[idx] = f2bf(src[n * ld + off + kk]);
        }
    } else if (blk <= 7) {                    // -------- product GEMMs P@Q
        const float* P; const float* Q; int ldp; u16* D;
        if (blk == 4)      { P = n_w1 + 128;           ldp = 256; Q = e_w2;         D = wb;              }
        else if (blk == 5) { P = n_w1 + 32768 + 128;   ldp = 256; Q = e_w2 + 16384; D = wb + 5 * 16384;  }
        else if (blk == 6) { P = e_w1 + 128 * 257;     ldp = 257; Q = n_w2;         D = wb + 2 * 16384;  }
        else               { P = e_w1 + 128 * 257 + 128; ldp = 257; Q = n_w2;       D = wb + 3 * 16384;  }
        u16* qt = (u16*)smem;                 // Q transposed [k][c], padded
        u16* tl = (u16*)(smem + 34816);
        for (int idx = tid; idx < 16384; idx += 256) {
            int c = idx >> 7, kd = idx & 127;
            qt[kd * LDP + c] = f2bf(Q[idx]);
        }
        __syncthreads();
        for (int t = 0; t < 2; ++t) {
            int r0 = (w * 2 + t) * 16;
            floatx4 acc[8] = {};
#pragma unroll
            for (int kb = 0; kb < 4; ++kb) {
                short8 a = frag_cvt(P, r0, ldp, kb, lane);
#pragma unroll
                for (int nt = 0; nt < 8; ++nt)
                    acc[nt] = mfma16(a, sfrag(qt, nt * 16, kb, lane), acc[nt]);
            }
            u16* slot = tl + w * 16 * LDP;
            tile_store(slot, acc, lane); WVB();
            tile_flush(slot, D + (size_t)r0 * 128, lane); WVB();
        }
    } else if (blk == 8) {                    // -------- rx = z0@n1a0^T + n_b1_0
        int r0 = w * 16;
        floatx4 acc[8] = {};
#pragma unroll
        for (int kb = 0; kb < 4; ++kb) {
            short8 a = frag_cvt(z0, r0, 128, kb, lane);
#pragma unroll
            for (int nt = 0; nt < 8; ++nt)
                acc[nt] = mfma16(a, frag_cvt(n_w1, nt * 16, 256, kb, lane), acc[nt]);
        }
#pragma unroll
        for (int nt = 0; nt < 8; ++nt) {
            int cg = nt * 16 + col; float bv = n_b1[cg];
#pragma unroll
            for (int r = 0; r < 4; ++r) rx[(r0 + qd * 4 + r) * 128 + cg] = acc[nt][r] + bv;
        }
    } else if (blk == 9 || blk == 10) {       // -------- rci/rcj = (z0+n_b2_0)@W1{a,b}1^T (+e_b1_1)
        int r0 = w * 16;
        const float* Wp = (blk == 9) ? (e_w1 + 128 * 257) : (e_w1 + 128 * 257 + 128);
        float* dst = (blk == 9) ? rci : rcj;
        floatx4 acc[8] = {};
#pragma unroll
        for (int kb = 0; kb < 4; ++kb) {
            short8 a;
            int rr = (r0 + (lane & 15)) * 128, kk = kb * 32 + (lane >> 4) * 8;
#pragma unroll
            for (int j = 0; j < 8; ++j) a[j] = (short)f2bf(z0[rr + kk + j] + n_b2[kk + j]);
#pragma unroll
            for (int nt = 0; nt < 8; ++nt)
                acc[nt] = mfma16(a, frag_cvt(Wp, nt * 16, 257, kb, lane), acc[nt]);
        }
#pragma unroll
        for (int nt = 0; nt < 8; ++nt) {
            int cg = nt * 16 + col;
            float bv = (blk == 9) ? e_b1[128 + cg] : 0.0f;
#pragma unroll
            for (int r = 0; r < 4; ++r) dst[(r0 + qd * 4 + r) * 128 + cg] = acc[nt][r] + bv;
        }
    } else if (blk == 11) {                   // -------- ci0/cj0 (64-row tables)
        u16* tl = (u16*)(smem + 34816);
        int r0 = w * 16;
        floatx4 a1[8] = {}, a2[8] = {};
#pragma unroll
        for (int kb = 0; kb < 4; ++kb) {
            short8 a = frag_cvt(z0, r0, 128, kb, lane);
#pragma unroll
            for (int nt = 0; nt < 8; ++nt) {
                a1[nt] = mfma16(a, frag_cvt(e_w1,       nt * 16, 257, kb, lane), a1[nt]);
                a2[nt] = mfma16(a, frag_cvt(e_w1 + 128, nt * 16, 257, kb, lane), a2[nt]);
            }
        }
#pragma unroll
        for (int nt = 0; nt < 8; ++nt) {
            float bv = e_b1[nt * 16 + col];
#pragma unroll
            for (int r = 0; r < 4; ++r) a1[nt][r] += bv;
        }
        u16* slot = tl + w * 16 * LDP;
        tile_store(slot, a1, lane); WVB();
        tile_flush(slot, ci0 + (size_t)r0 * 128, lane); WVB();
        tile_store(slot, a2, lane); WVB();
        tile_flush(slot, cj0 + (size_t)r0 * 128, lane);
    } else {                                  // -------- vb2 + wl
        int k = tid >> 7, c = tid & 127;
        float s = 0.0f;
        for (int n = 0; n < 128; ++n)
            s += n_w1[k * 32768 + c * 256 + 128 + n] * e_b2[k * 128 + n];
        vb2[tid] = s;
        wl[tid]  = e_w1[k * 128 * 257 + c * 257 + 256];
    }
}

// ---------------------------------------------------------------------------
// Edge gather: one wave handles (q, 4 consecutive b)
// ---------------------------------------------------------------------------
__global__ __launch_bounds__(256) void k_edge(const u16* __restrict__ ci,
                                              const u16* __restrict__ cj,
                                              int ci_bs, int ci_qs,
                                              int cj_bs, int cj_ts,
                                              const int* __restrict__ ofs,
                                              const int* __restrict__ tgt_s,
                                              const float* __restrict__ a_s,
                                              const float* __restrict__ wl,
                                              u16* __restrict__ S) {
    int tid = threadIdx.x, lane = tid & 63, w = tid >> 6;
    int gw = blockIdx.x * 4 + w;
    int q = gw & (NQ_ - 1), b0 = (gw >> 10) * 4;
    const u32* cjp0 = (const u32*)cj + (size_t)(b0 + 0) * cj_bs;
    const u32* cjp1 = (const u32*)cj + (size_t)(b0 + 1) * cj_bs;
    const u32* cjp2 = (const u32*)cj + (size_t)(b0 + 2) * cj_bs;
    const u32* cjp3 = (const u32*)cj + (size_t)(b0 + 3) * cj_bs;
    float cix[4], ciy[4];
#pragma unroll
    for (int i = 0; i < 4; ++i) {
        u32 cv = ((const u32*)ci)[(size_t)(b0 + i) * ci_bs + (size_t)q * ci_qs + lane];
        cix[i] = bf2f((u16)(cv & 0xffff)); ciy[i] = bf2f((u16)(cv >> 16));
    }
    float2 wl2 = ((const float2*)wl)[lane];
    int st = ofs[q], en = ofs[q + 1];
    float ax[4] = {0, 0, 0, 0}, ay[4] = {0, 0, 0, 0};
    for (int idx = st; idx < en; ++idx) {
        int t = tgt_s[idx];
        float a = a_s[idx];
        size_t ro = (size_t)t * cj_ts + lane;
        u32 j0 = cjp0[ro], j1 = cjp1[ro], j2 = cjp2[ro], j3 = cjp3[ro];
        float wx = a * wl2.x, wy = a * wl2.y;
        ax[0] += fmaxf(cix[0] + bf2f((u16)(j0 & 0xffff)) + wx, 0.f);
        ay[0] += fmaxf(ciy[0] + bf2f((u16)(j0 >> 16))    + wy, 0.f);
        ax[1] += fmaxf(cix[1] + bf2f((u16)(j1 & 0xffff)) + wx, 0.f);
        ay[1] += fmaxf(ciy[1] + bf2f((u16)(j1 >> 16))    + wy, 0.f);
        ax[2] += fmaxf(cix[2] + bf2f((u16)(j2 & 0xffff)) + wx, 0.f);
        ay[2] += fmaxf(ciy[2] + bf2f((u16)(j2 >> 16))    + wy, 0.f);
        ax[3] += fmaxf(cix[3] + bf2f((u16)(j3 & 0xffff)) + wx, 0.f);
        ay[3] += fmaxf(ciy[3] + bf2f((u16)(j3 >> 16))    + wy, 0.f);
    }
    u32* Sp = (u32*)S;
#pragma unroll
    for (int i = 0; i < 4; ++i)
        Sp[((size_t)(b0 + i) * NQ_ + q) * 64 + lane] =
            (u32)f2bf(ax[i]) | ((u32)f2bf(ay[i]) << 16);
}

// ---------------------------------------------------------------------------
// node0: x=LN(relu(S@Wc0 + rx + deg*vb2)); h0 = z0+n_b2_0 + x@n2_0 -> hbf +
//        mean into out; ci1 = x@Wd + rci; cj1 = x@We + rcj
// 512 blocks x 256 thr; 128 rows/block, 2 row-tiles per wave
// ---------------------------------------------------------------------------
__global__ __launch_bounds__(256, 2) void k_node0(const u16* __restrict__ S,
                                                  const u16* __restrict__ wb,
                                                  const float* __restrict__ rx,
                                                  const float* __restrict__ vb2,
                                                  const float* __restrict__ degf,
                                                  const float* __restrict__ z0,
                                                  const float* __restrict__ n_b2,
                                                  const float* __restrict__ rci,
                                                  const float* __restrict__ rcj,
                                                  const float* __restrict__ g,
                                                  const float* __restrict__ bb,
                                                  u16* __restrict__ hbf,
                                                  u16* __restrict__ ci1,
                                                  u16* __restrict__ cj1,
                                                  float* __restrict__ out) {
    __shared__ u16 wbuf[128 * LDP];
    __shared__ u16 xt[8][16 * LDP];
    __shared__ float rsum[4][128];
    int tid = threadIdx.x, lane = tid & 63, w = tid >> 6;
    int col = lane & 15, qd = lane >> 4;
    int rowbase = blockIdx.x * 128 + w * 32;
    int b = blockIdx.x >> 3;

    // ---- phase A: x = LN(relu(S@Wc0 + rx + deg*vb2))
    stage_w(wbuf, wb, tid);
    __syncthreads();
    floatx4 xa[2][8] = {};
#pragma unroll
    for (int kb = 0; kb < 4; ++kb) {
        short8 Bv[8];
#pragma unroll
        for (int nt = 0; nt < 8; ++nt) Bv[nt] = sfrag(wbuf, nt * 16, kb, lane);
#pragma unroll
        for (int t = 0; t < 2; ++t) {
            short8 a = gfrag(S, rowbase + t * 16, kb, lane);
#pragma unroll
            for (int nt = 0; nt < 8; ++nt) xa[t][nt] = mfma16(a, Bv[nt], xa[t][nt]);
        }
    }
#pragma unroll
    for (int t = 0; t < 2; ++t) {
#pragma unroll
        for (int nt = 0; nt < 8; ++nt) {
            int cg = nt * 16 + col;
            float base = rx[b * 128 + cg], vb = vb2[cg];
#pragma unroll
            for (int r = 0; r < 4; ++r) {
                int row = rowbase + t * 16 + qd * 4 + r;
                xa[t][nt][r] = fmaxf(xa[t][nt][r] + base + degf[row & (NQ_ - 1)] * vb, 0.f);
            }
        }
#pragma unroll
        for (int r = 0; r < 4; ++r) {
            float s = 0.f, s2 = 0.f;
#pragma unroll
            for (int nt = 0; nt < 8; ++nt) { float v = xa[t][nt][r]; s += v; s2 += v * v; }
#pragma unroll
            for (int o = 1; o < 16; o <<= 1) { s += __shfl_xor(s, o, 64); s2 += __shfl_xor(s2, o, 64); }
            float mu = s * (1.f / 128.f), var = s2 * (1.f / 128.f) - mu * mu;
            float rs = rsqrtf(var + 1e-5f);
#pragma unroll
            for (int nt = 0; nt < 8; ++nt) {
                int cg = nt * 16 + col;
                xa[t][nt][r] = (xa[t][nt][r] - mu) * rs * g[cg] + bb[cg];
            }
        }
        tile_store(&xt[w * 2 + t][0], xa[t], lane);
    }
    __syncthreads();

    // ---- phase B: hv = x@n2_0 + (z0[b]+n_b2); hbf + mean->out
    stage_w(wbuf, wb + 1 * 16384, tid);
    __syncthreads();
    floatx4 ha[2][8] = {};
#pragma unroll
    for (int kb = 0; kb < 4; ++kb) {
        short8 Bv[8];
#pragma unroll
        for (int nt = 0; nt < 8; ++nt) Bv[nt] = sfrag(wbuf, nt * 16, kb, lane);
#pragma unroll
        for (int t = 0; t < 2; ++t) {
            short8 a = sfrag(&xt[w * 2 + t][0], 0, kb, lane);
#pragma unroll
            for (int nt = 0; nt < 8; ++nt) ha[t][nt] = mfma16(a, Bv[nt], ha[t][nt]);
        }
    }
    float s8[8] = {0, 0, 0, 0, 0, 0, 0, 0};
#pragma unroll
    for (int t = 0; t < 2; ++t)
#pragma unroll
        for (int nt = 0; nt < 8; ++nt) {
            int cg = nt * 16 + col;
            float hp = z0[b * 128 + cg] + n_b2[cg];
#pragma unroll
            for (int r = 0; r < 4; ++r) {
                float hv = ha[t][nt][r] + hp;
                ha[t][nt][r] = hv;
                s8[nt] += hv;
            }
        }
#pragma unroll
    for (int nt = 0; nt < 8; ++nt) {
        s8[nt] += __shfl_xor(s8[nt], 16, 64);
        s8[nt] += __shfl_xor(s8[nt], 32, 64);
    }
    if (lane < 16) {
#pragma unroll
        for (int nt = 0; nt < 8; ++nt) rsum[w][nt * 16 + lane] = s8[nt];
    }
    __syncthreads();                      // MFMAs done; wbuf free; rsum ready
    if (tid < 128) {
        float v = rsum[0][tid] + rsum[1][tid] + rsum[2][tid] + rsum[3][tid];
        atomicAdd(out + b * 128 + tid, v * (1.f / 1024.f));
    }
#pragma unroll
    for (int t = 0; t < 2; ++t) tile_store(wbuf + (w * 2 + t) * 16 * LDP, ha[t], lane);
    WVB();
#pragma unroll
    for (int t = 0; t < 2; ++t)
        tile_flush(wbuf + (w * 2 + t) * 16 * LDP, hbf + (size_t)(rowbase + t * 16) * 128, lane);
    __syncthreads();

    // ---- phase C: ci1 = x@Wd + rci
    stage_w(wbuf, wb + 2 * 16384, tid);
    __syncthreads();
    floatx4 ca[2][8] = {};
#pragma unroll
    for (int kb = 0; kb < 4; ++kb) {
        short8 Bv[8];
#pragma unroll
        for (int nt = 0; nt < 8; ++nt) Bv[nt] = sfrag(wbuf, nt * 16, kb, lane);
#pragma unroll
        for (int t = 0; t < 2; ++t) {
            short8 a = sfrag(&xt[w * 2 + t][0], 0, kb, lane);
#pragma unroll
            for (int nt = 0; nt < 8; ++nt) ca[t][nt] = mfma16(a, Bv[nt], ca[t][nt]);
        }
    }
#pragma unroll
    for (int t = 0; t < 2; ++t)
#pragma unroll
        for (int nt = 0; nt < 8; ++nt) {
            float rc = rci[b * 128 + nt * 16 + col];
#pragma unroll
            for (int r = 0; r < 4; ++r) ca[t][nt][r] += rc;
        }
    __syncthreads();
#pragma unroll
    for (int t = 0; t < 2; ++t) tile_store(wbuf + (w * 2 + t) * 16 * LDP, ca[t], lane);
    WVB();
#pragma unroll
    for (int t = 0; t < 2; ++t)
        tile_flush(wbuf + (w * 2 + t) * 16 * LDP, ci1 + (size_t)(rowbase + t * 16) * 128, lane);
    __syncthreads();

    // ---- phase D: cj1 = x@We + rcj
    stage_w(wbuf, wb + 3 * 16384, tid);
    __syncthreads();
    floatx4 da[2][8] = {};
#pragma unroll
    for (int kb = 0; kb < 4; ++kb) {
        short8 Bv[8];
#pragma unroll
        for (int nt = 0; nt < 8; ++nt) Bv[nt] = sfrag(wbuf, nt * 16, kb, lane);
#pragma unroll
        for (int t = 0; t < 2; ++t) {
            short8 a = sfrag(&xt[w * 2 + t][0], 0, kb, lane);
#pragma unroll
            for (int nt = 0; nt < 8; ++nt) da[t][nt] = mfma16(a, Bv[nt], da[t][nt]);
        }
    }
#pragma unroll
    for (int t = 0; t < 2; ++t)
#pragma unroll
        for (int nt = 0; nt < 8; ++nt) {
            float rc = rcj[b * 128 + nt * 16 + col];
#pragma unroll
            for (int r = 0; r < 4; ++r) da[t][nt][r] += rc;
        }
    __syncthreads();
#pragma unroll
    for (int t = 0; t < 2; ++t) tile_store(wbuf + (w * 2 + t) * 16 * LDP, da[t], lane);
    WVB();
#pragma unroll
    for (int t = 0; t < 2; ++t)
        tile_flush(wbuf + (w * 2 + t) * 16 * LDP, cj1 + (size_t)(rowbase + t * 16) * 128, lane);
}

// ---------------------------------------------------------------------------
// node1: x = LN(relu(hbf@n1a1 + S@Wc1 + deg*vb2_1 + n_b1_1));
//        out += mean_q(x@n2_1) + n_b2_1
// ---------------------------------------------------------------------------
__global__ __launch_bounds__(256, 2) void k_node1(const u16* __restrict__ S,
                                                  const u16* __restrict__ hbf,
                                                  const u16* __restrict__ wb,
                                                  const float* __restrict__ vb2,
                                                  const float* __restrict__ degf,
                                                  const float* __restrict__ n_b1,
                                                  const float* __restrict__ g,
                                                  const float* __restrict__ bb,
                                                  const float* __restrict__ n_b2,
                                                  float* __restrict__ out) {
    __shared__ u16 wbuf[128 * LDP];
    __shared__ u16 xt[8][16 * LDP];
    __shared__ float rsum[4][128];
    int tid = threadIdx.x, lane = tid & 63, w = tid >> 6;
    int col = lane & 15, qd = lane >> 4;
    int rowbase = blockIdx.x * 128 + w * 32;
    int b = blockIdx.x >> 3;

    // ---- x accumulation: hbf@n1a1 then S@Wc1
    stage_w(wbuf, wb + 4 * 16384, tid);
    __syncthreads();
    floatx4 xa[2][8] = {};
#pragma unroll
    for (int kb = 0; kb < 4; ++kb) {
        short8 Bv[8];
#pragma unroll
        for (int nt = 0; nt < 8; ++nt) Bv[nt] = sfrag(wbuf, nt * 16, kb, lane);
#pragma unroll
        for (int t = 0; t < 2; ++t) {
            short8 a = gfrag(hbf, rowbase + t * 16, kb, lane);
#pragma unroll
            for (int nt = 0; nt < 8; ++nt) xa[t][nt] = mfma16(a, Bv[nt], xa[t][nt]);
        }
    }
    __syncthreads();
    stage_w(wbuf, wb + 5 * 16384, tid);
    __syncthreads();
#pragma unroll
    for (int kb = 0; kb < 4; ++kb) {
        short8 Bv[8];
#pragma unroll
        for (int nt = 0; nt < 8; ++nt) Bv[nt] = sfrag(wbuf, nt * 16, kb, lane);
#pragma unroll
        for (int t = 0; t < 2; ++t) {
            short8 a = gfrag(S, rowbase + t * 16, kb, lane);
#pragma unroll
            for (int nt = 0; nt < 8; ++nt) xa[t][nt] = mfma16(a, Bv[nt], xa[t][nt]);
        }
    }
#pragma unroll
    for (int t = 0; t < 2; ++t) {
#pragma unroll
        for (int nt = 0; nt < 8; ++nt) {
            int cg = nt * 16 + col;
            float base = n_b1[cg], vb = vb2[cg];
#pragma unroll
            for (int r = 0; r < 4; ++r) {
                int row = rowbase + t * 16 + qd * 4 + r;
                xa[t][nt][r] = fmaxf(xa[t][nt][r] + base + degf[row & (NQ_ - 1)] * vb, 0.f);
            }
        }
#pragma unroll
        for (int r = 0; r < 4; ++r) {
            float s = 0.f, s2 = 0.f;
#pragma unroll
            for (int nt = 0; nt < 8; ++nt) { float v = xa[t][nt][r]; s += v; s2 += v * v; }
#pragma unroll
            for (int o = 1; o < 16; o <<= 1) { s += __shfl_xor(s, o, 64); s2 += __shfl_xor(s2, o, 64); }
            float mu = s * (1.f / 128.f), var = s2 * (1.f / 128.f) - mu * mu;
            float rs = rsqrtf(var + 1e-5f);
#pragma unroll
            for (int nt = 0; nt < 8; ++nt) {
                int cg = nt * 16 + col;
                xa[t][nt][r] = (xa[t][nt][r] - mu) * rs * g[cg] + bb[cg];
            }
        }
        tile_store(&xt[w * 2 + t][0], xa[t], lane);
    }
    __syncthreads();

    // ---- mean(x@n2_1) -> out
    stage_w(wbuf, wb + 6 * 16384, tid);
    __syncthreads();
    floatx4 ma[2][8] = {};
#pragma unroll
    for (int kb = 0; kb < 4; ++kb) {
        short8 Bv[8];
#pragma unroll
        for (int nt = 0; nt < 8; ++nt) Bv[nt] = sfrag(wbuf, nt * 16, kb, lane);
#pragma unroll
        for (int t = 0; t < 2; ++t) {
            short8 a = sfrag(&xt[w * 2 + t][0], 0, kb, lane);
#pragma unroll
            for (int nt = 0; nt < 8; ++nt) ma[t][nt] = mfma16(a, Bv[nt], ma[t][nt]);
        }
    }
    float s8[8] = {0, 0, 0, 0, 0, 0, 0, 0};
#pragma unroll
    for (int t = 0; t < 2; ++t)
#pragma unroll
        for (int nt = 0; nt < 8; ++nt)
#pragma unroll
            for (int r = 0; r < 4; ++r) s8[nt] += ma[t][nt][r];
#pragma unroll
    for (int nt = 0; nt < 8; ++nt) {
        s8[nt] += __shfl_xor(s8[nt], 16, 64);
        s8[nt] += __shfl_xor(s8[nt], 32, 64);
    }
    if (lane < 16) {
#pragma unroll
        for (int nt = 0; nt < 8; ++nt) rsum[w][nt * 16 + lane] = s8[nt];
    }
    __syncthreads();
    if (tid < 128) {
        float v = rsum[0][tid] + rsum[1][tid] + rsum[2][tid] + rsum[3][tid];
        atomicAdd(out + b * 128 + tid, v * (1.f / 1024.f) + n_b2[tid] * 0.125f);
    }
}

// ---------------------------------------------------------------------------
extern "C" void kernel_launch(void* const* d_in, const int* in_sizes, int n_in,
                              void* d_out, int out_size, void* d_ws, size_t ws_size,
                              hipStream_t stream) {
    const float* z0    = (const float*)d_in[0];
    const int*   ei    = (const int*)d_in[1];
    const float* attr  = (const float*)d_in[2];
    const float* e_w1  = (const float*)d_in[4];
    const float* e_b1  = (const float*)d_in[5];
    const float* e_w2  = (const float*)d_in[6];
    const float* e_b2  = (const float*)d_in[7];
    const float* n_w1  = (const float*)d_in[8];
    const float* n_b1  = (const float*)d_in[9];
    const float* ln_g  = (const float*)d_in[10];
    const float* ln_b  = (const float*)d_in[11];
    const float* n_w2  = (const float*)d_in[12];
    const float* n_b2  = (const float*)d_in[13];
    float* out = (float*)d_out;

    const size_t H = (size_t)M_ * L_;            // 8388608
    float* f    = (float*)d_ws;
    float* degf = f;                             // 1024
    float* a_s  = degf + 1024;                   // 8192
    float* wl   = a_s + 8192;                    // 256
    float* vb2  = wl + 256;                      // 256
    float* rx   = vb2 + 256;                     // 8192
    float* rci  = rx + 8192;                     // 8192
    float* rcj  = rci + 8192;                    // 8192
    int*   ofs   = (int*)(rcj + 8192);           // 1025 (pad 1056)
    int*   tgt_s = ofs + 1056;                   // 8192
    u16*   wb    = (u16*)(tgt_s + 8192);         // 7*16384
    u16*   ci0   = wb + 7 * 16384;               // 8192
    u16*   cj0   = ci0 + 8192;                   // 8192
    u16*   S     = cj0 + 8192;                   // H
    u16*   hbf   = S + H;                        // H
    u16*   ci1   = hbf + H;                      // H
    u16*   cj1   = ci1 + H;                      // H

    hipMemsetAsync(out, 0, 8192 * sizeof(float), stream);

    k_setup<<<13, 256, 0, stream>>>(ei, attr, z0, e_w1, e_b1, e_w2, e_b2,
                                    n_w1, n_b1, n_w2, n_b2,
                                    ofs, tgt_s, a_s, degf, wb, wl, vb2,
                                    rx, rci, rcj, ci0, cj0);

    // round 0 edge gather (broadcast tables: q/t strides 0)
    k_edge<<<4096, 256, 0, stream>>>(ci0, cj0, 64, 0, 64, 0,
                                     ofs, tgt_s, a_s, wl, S);
    k_node0<<<512, 256, 0, stream>>>(S, wb, rx, vb2, degf, z0, n_b2,
                                     rci, rcj, ln_g, ln_b,
                                     hbf, ci1, cj1, out);
    // round 1 edge gather (full strides)
    k_edge<<<4096, 256, 0, stream>>>(ci1, cj1, NQ_ * 64, 64, NQ_ * 64, 64,
                                     ofs, tgt_s, a_s, wl + 128, S);
    k_node1<<<512, 256, 0, stream>>>(S, hbf, wb, vb2 + 128, degf,
                                     n_b1 + 128, ln_g + 128, ln_b + 128,
                                     n_b2 + 128, out);
}

// Round 6
// 190.870 us; speedup vs baseline: 3.4055x; 1.0326x over previous
//
#include <hip/hip_runtime.h>

#define B_   64
#define NQ_  1024
#define L_   128
#define E_   8192
#define M_   (B_*NQ_)
#define LDP  136        // padded LDS row stride (shorts): 272 B, 2-way conflicts only

typedef unsigned short u16;
typedef unsigned int   u32;
typedef __attribute__((ext_vector_type(8))) short short8;   // 8 bf16
typedef __attribute__((ext_vector_type(4))) float floatx4;  // MFMA C/D

#define WVB() __builtin_amdgcn_wave_barrier()

__device__ __forceinline__ u16 f2bf(float f) {
    union { float f; u32 u; } v; v.f = f;
    return (u16)((v.u + 0x7fffu + ((v.u >> 16) & 1u)) >> 16);
}
__device__ __forceinline__ float bf2f(u16 u) {
    union { u32 u; float f; } v; v.u = ((u32)u) << 16;
    return v.f;
}
__device__ __forceinline__ floatx4 mfma16(short8 a, short8 b, floatx4 c) {
    return __builtin_amdgcn_mfma_f32_16x16x32_bf16(a, b, c, 0, 0, 0);
}
__device__ __forceinline__ short8 gfrag(const u16* base, int r0, int kb, int lane) {
    return *(const short8*)(base + (size_t)(r0 + (lane & 15)) * 128 + kb * 32 + (lane >> 4) * 8);
}
__device__ __forceinline__ short8 sfrag(const u16* t, int r0, int kb, int lane) {
    return *(const short8*)(t + (r0 + (lane & 15)) * LDP + kb * 32 + (lane >> 4) * 8);
}
__device__ __forceinline__ short8 frag_cvt(const float* base, int r0, int ld, int kb, int lane) {
    const float* p = base + (size_t)(r0 + (lane & 15)) * ld + kb * 32 + (lane >> 4) * 8;
    short8 s;
#pragma unroll
    for (int j = 0; j < 8; ++j) s[j] = (short)f2bf(p[j]);
    return s;
}
__device__ __forceinline__ void tile_store(u16* t, const floatx4* acc, int lane) {
    int col = lane & 15, qd = lane >> 4;
#pragma unroll
    for (int nt = 0; nt < 8; ++nt)
#pragma unroll
        for (int r = 0; r < 4; ++r)
            t[(qd * 4 + r) * LDP + nt * 16 + col] = f2bf(acc[nt][r]);
}
__device__ __forceinline__ void tile_flush(const u16* t, u16* g, int lane) {
#pragma unroll
    for (int it = 0; it < 4; ++it) {
        int chunk = it * 64 + lane, row = chunk >> 4, c8 = chunk & 15;
        *(uint4*)(g + (size_t)row * 128 + c8 * 8) = *(const uint4*)(t + row * LDP + c8 * 8);
    }
}
__device__ __forceinline__ void stage_w(u16* wbuf, const u16* g, int tid) {
    const uint4* g4 = (const uint4*)g;
#pragma unroll
    for (int i = 0; i < 8; ++i) {
        int idx = tid + i * 256, row = idx >> 4, c8 = idx & 15;
        *(uint4*)&wbuf[row * LDP + c8 * 8] = g4[idx];
    }
}

// ---------------------------------------------------------------------------
// Setup: blk0 CSR; blk1-2 n2 bf16 cvt; blk3-7 product GEMMs (Wc0,Wc1,Wd,We,Wf);
// blk8 rx; blk9-11 rci/rcj/rh; blk12 c0 = ci0+cj0 (combined round-0 table);
// blk13 vb2 + wl + zero mx0
// wb slots: 0=Wc0 1=n2_0 2=Wd 3=We 4=Wf 5=Wc1 6=n2_1
// ---------------------------------------------------------------------------
__global__ __launch_bounds__(256) void k_setup(const int* __restrict__ ei,
                                               const float* __restrict__ attr,
                                               const float* __restrict__ z0,
                                               const float* __restrict__ e_w1,
                                               const float* __restrict__ e_b1,
                                               const float* __restrict__ e_w2,
                                               const float* __restrict__ e_b2,
                                               const float* __restrict__ n_w1,
                                               const float* __restrict__ n_b1,
                                               const float* __restrict__ n_w2,
                                               const float* __restrict__ n_b2,
                                               int* __restrict__ ofs,
                                               int* __restrict__ tgt_s,
                                               float* __restrict__ a_s,
                                               float* __restrict__ degf,
                                               u16* __restrict__ wb,
                                               float* __restrict__ wl,
                                               float* __restrict__ vb2,
                                               float* __restrict__ rx,
                                               float* __restrict__ rci,
                                               float* __restrict__ rcj,
                                               float* __restrict__ rh,
                                               float* __restrict__ mx0,
                                               u16* __restrict__ c0t) {
    __shared__ __align__(16) char smem[52608];
    int tid = threadIdx.x, blk = blockIdx.x;
    int lane = tid & 63, w = tid >> 6, col = lane & 15, qd = lane >> 4;

    if (blk == 0) {                               // CSR build
        int* cnt  = (int*)smem;
        int* wsum = cnt + 1024;
        int* flag = wsum + 8;
#pragma unroll
        for (int i = 0; i < 4; ++i) cnt[tid + i * 256] = 0;
        if (tid == 0) *flag = 1;
        __syncthreads();
        if (tid < 100 && ei[2 * tid + 1] != 0) atomicAnd(flag, 0);
        __syncthreads();
        int i64 = *flag;
        for (int e = tid; e < E_; e += 256) {
            int s = i64 ? ei[2 * e] : ei[e];
            atomicAdd(&cnt[s], 1);
        }
        __syncthreads();
        int q0 = tid * 4;
        int c0 = cnt[q0], c1 = cnt[q0 + 1], c2 = cnt[q0 + 2], c3 = cnt[q0 + 3];
        int tsum = c0 + c1 + c2 + c3, incl = tsum;
#pragma unroll
        for (int o = 1; o < 64; o <<= 1) {
            int t = __shfl_up(incl, o, 64);
            if (lane >= o) incl += t;
        }
        if (lane == 63) wsum[w] = incl;
        __syncthreads();
        int wo = 0;
        for (int i = 0; i < w; ++i) wo += wsum[i];
        int base = wo + incl - tsum;
        ofs[q0] = base; ofs[q0 + 1] = base + c0;
        ofs[q0 + 2] = base + c0 + c1; ofs[q0 + 3] = base + c0 + c1 + c2;
        degf[q0] = (float)c0; degf[q0 + 1] = (float)c1;
        degf[q0 + 2] = (float)c2; degf[q0 + 3] = (float)c3;
        if (tid == 0) ofs[NQ_] = E_;
        __syncthreads();
        cnt[q0] = base; cnt[q0 + 1] = base + c0;
        cnt[q0 + 2] = base + c0 + c1; cnt[q0 + 3] = base + c0 + c1 + c2;
        __syncthreads();
        for (int e = tid; e < E_; e += 256) {
            int s = i64 ? ei[2 * e]        : ei[e];
            int t = i64 ? ei[2 * (E_ + e)] : ei[E_ + e];
            int pos = atomicAdd(&cnt[s], 1);
            tgt_s[pos] = t;
            a_s[pos]   = attr[e];
        }
    } else if (blk <= 2) {                        // n2_0 / n2_1 bf16 cvt
        const float* src = (blk == 1) ? n_w2 : (n_w2 + 16384);
        u16* dst = wb + ((blk == 1) ? 1 : 6) * 16384;
        for (int idx = tid; idx < 16384; idx += 256) dst[idx] = f2bf(src[idx]);
    } else if (blk <= 7) {                        // product GEMMs D = P @ Q
        const float* P; const float* Q; int ldp; u16* D;
        switch (blk) {
            case 3: P = n_w1 + 128;             ldp = 256; Q = e_w2;         D = wb;             break;
            case 4: P = n_w1 + 32768 + 128;     ldp = 256; Q = e_w2 + 16384; D = wb + 5 * 16384; break;
            case 5: P = e_w1 + 128 * 257;       ldp = 257; Q = n_w2;         D = wb + 2 * 16384; break;
            case 6: P = e_w1 + 128 * 257 + 128; ldp = 257; Q = n_w2;         D = wb + 3 * 16384; break;
            default:P = n_w1 + 32768;           ldp = 256; Q = n_w2;         D = wb + 4 * 16384; break;
        }
        u16* qt = (u16*)smem;                     // Q^T staged, padded
        u16* tl = (u16*)(smem + 34816);
        for (int idx = tid; idx < 16384; idx += 256) {
            int c = idx >> 7, kd = idx & 127;
            qt[kd * LDP + c] = f2bf(Q[idx]);
        }
        __syncthreads();
        for (int t = 0; t < 2; ++t) {
            int r0 = (w * 2 + t) * 16;
            floatx4 acc[8] = {};
#pragma unroll
            for (int kb = 0; kb < 4; ++kb) {
                short8 a = frag_cvt(P, r0, ldp, kb, lane);
#pragma unroll
                for (int nt = 0; nt < 8; ++nt)
                    acc[nt] = mfma16(a, sfrag(qt, nt * 16, kb, lane), acc[nt]);
            }
            u16* slot = tl + w * 16 * LDP;
            tile_store(slot, acc, lane); WVB();
            tile_flush(slot, D + (size_t)r0 * 128, lane); WVB();
        }
    } else if (blk == 8) {                        // rx = z0@n1a0^T + n_b1_0
        int r0 = w * 16;
        floatx4 acc[8] = {};
#pragma unroll
        for (int kb = 0; kb < 4; ++kb) {
            short8 a = frag_cvt(z0, r0, 128, kb, lane);
#pragma unroll
            for (int nt = 0; nt < 8; ++nt)
                acc[nt] = mfma16(a, frag_cvt(n_w1, nt * 16, 256, kb, lane), acc[nt]);
        }
#pragma unroll
        for (int nt = 0; nt < 8; ++nt) {
            int cg = nt * 16 + col; float bv = n_b1[cg];
#pragma unroll
            for (int r = 0; r < 4; ++r) rx[(r0 + qd * 4 + r) * 128 + cg] = acc[nt][r] + bv;
        }
    } else if (blk <= 11) {                       // rci/rcj/rh = (z0+n_b2_0)@W^T (+bias)
        int r0 = w * 16;
        const float* Wp; int ld; const float* bias; float* dst;
        if (blk == 9)       { Wp = e_w1 + 128 * 257;       ld = 257; bias = e_b1 + 128; dst = rci; }
        else if (blk == 10) { Wp = e_w1 + 128 * 257 + 128; ld = 257; bias = nullptr;    dst = rcj; }
        else                { Wp = n_w1 + 32768;           ld = 256; bias = n_b1 + 128; dst = rh;  }
        floatx4 acc[8] = {};
#pragma unroll
        for (int kb = 0; kb < 4; ++kb) {
            short8 a;
            int rr = (r0 + (lane & 15)) * 128, kk = kb * 32 + (lane >> 4) * 8;
#pragma unroll
            for (int j = 0; j < 8; ++j) a[j] = (short)f2bf(z0[rr + kk + j] + n_b2[kk + j]);
#pragma unroll
            for (int nt = 0; nt < 8; ++nt)
                acc[nt] = mfma16(a, frag_cvt(Wp, nt * 16, ld, kb, lane), acc[nt]);
        }
#pragma unroll
        for (int nt = 0; nt < 8; ++nt) {
            int cg = nt * 16 + col;
            float bv = bias ? bias[cg] : 0.0f;
#pragma unroll
            for (int r = 0; r < 4; ++r) dst[(r0 + qd * 4 + r) * 128 + cg] = acc[nt][r] + bv;
        }
    } else if (blk == 12) {                       // c0 = z0@W1a0^T + z0@W1b0^T + e_b1_0
        u16* tl = (u16*)(smem + 34816);
        int r0 = w * 16;
        floatx4 a1[8] = {};
#pragma unroll
        for (int kb = 0; kb < 4; ++kb) {
            short8 a = frag_cvt(z0, r0, 128, kb, lane);
#pragma unroll
            for (int nt = 0; nt < 8; ++nt) {
                a1[nt] = mfma16(a, frag_cvt(e_w1,       nt * 16, 257, kb, lane), a1[nt]);
                a1[nt] = mfma16(a, frag_cvt(e_w1 + 128, nt * 16, 257, kb, lane), a1[nt]);
            }
        }
#pragma unroll
        for (int nt = 0; nt < 8; ++nt) {
            float bv = e_b1[nt * 16 + col];
#pragma unroll
            for (int r = 0; r < 4; ++r) a1[nt][r] += bv;
        }
        u16* slot = tl + w * 16 * LDP;
        tile_store(slot, a1, lane); WVB();
        tile_flush(slot, c0t + (size_t)r0 * 128, lane);
    } else {                                      // vb2 + wl + zero mx0
        int k = tid >> 7, c = tid & 127;
        float s = 0.0f;
        for (int n = 0; n < 128; ++n)
            s += n_w1[k * 32768 + c * 256 + 128 + n] * e_b2[k * 128 + n];
        vb2[tid] = s;
        wl[tid]  = e_w1[k * 128 * 257 + c * 257 + 256];
        for (int i = tid; i < 8192; i += 256) mx0[i] = 0.0f;
    }
}

// ---------------------------------------------------------------------------
// Edge gather. R0: combined broadcast table c0 (no per-edge gather loads).
// Else: wave handles one q x 8 batches (shared index stream).
// ---------------------------------------------------------------------------
template <bool R0>
__global__ __launch_bounds__(256) void k_edge(const u16* __restrict__ ci,
                                              const u16* __restrict__ cj,
                                              const int* __restrict__ ofs,
                                              const int* __restrict__ tgt_s,
                                              const float* __restrict__ a_s,
                                              const float* __restrict__ wl,
                                              u16* __restrict__ S) {
    int tid = threadIdx.x, lane = tid & 63, w = tid >> 6;
    int gw = blockIdx.x * 4 + w;
    int q = gw & (NQ_ - 1), bg = gw >> 10;        // bg in 0..7
    int bl[8];
#pragma unroll
    for (int i = 0; i < 4; ++i) { bl[i] = bg * 4 + i; bl[i + 4] = bg * 4 + i + 32; }
    float2 wl2 = ((const float2*)wl)[lane];
    int st = ofs[q], en = ofs[q + 1];
    float ax[8] = {}, ay[8] = {};
    if (R0) {
        float cx[8], cy[8];
#pragma unroll
        for (int i = 0; i < 8; ++i) {
            u32 cv = ((const u32*)ci)[(size_t)bl[i] * 64 + lane];
            cx[i] = bf2f((u16)(cv & 0xffff)); cy[i] = bf2f((u16)(cv >> 16));
        }
        for (int idx = st; idx < en; ++idx) {
            float a = a_s[idx];
            float wx = a * wl2.x, wy = a * wl2.y;
#pragma unroll
            for (int i = 0; i < 8; ++i) {
                ax[i] += fmaxf(cx[i] + wx, 0.f);
                ay[i] += fmaxf(cy[i] + wy, 0.f);
            }
        }
    } else {
        const u32* cjp[8];
        float cx[8], cy[8];
#pragma unroll
        for (int i = 0; i < 8; ++i) {
            cjp[i] = (const u32*)cj + (size_t)bl[i] * NQ_ * 64;
            u32 cv = ((const u32*)ci)[((size_t)bl[i] * NQ_ + q) * 64 + lane];
            cx[i] = bf2f((u16)(cv & 0xffff)); cy[i] = bf2f((u16)(cv >> 16));
        }
        for (int idx = st; idx < en; ++idx) {
            int t = tgt_s[idx];
            float a = a_s[idx];
            size_t ro = (size_t)t * 64 + lane;
            float wx = a * wl2.x, wy = a * wl2.y;
#pragma unroll
            for (int i = 0; i < 8; ++i) {
                u32 jv = cjp[i][ro];
                ax[i] += fmaxf(cx[i] + bf2f((u16)(jv & 0xffff)) + wx, 0.f);
                ay[i] += fmaxf(cy[i] + bf2f((u16)(jv >> 16))    + wy, 0.f);
            }
        }
    }
    u32* Sp = (u32*)S;
#pragma unroll
    for (int i = 0; i < 8; ++i)
        Sp[((size_t)bl[i] * NQ_ + q) * 64 + lane] =
            (u32)f2bf(ax[i]) | ((u32)f2bf(ay[i]) << 16);
}

// ---------------------------------------------------------------------------
// node0: x0 = LN(relu(S@Wc0 + rx + deg*vb2)); mx0[b] += sum_q x0;
//        t1 = x0@Wf + rh ; ci1 = x0@Wd + rci ; cj1 = x0@We + rcj
// ---------------------------------------------------------------------------
__global__ __launch_bounds__(256, 2) void k_node0(const u16* __restrict__ S,
                                                  const u16* __restrict__ wb,
                                                  const float* __restrict__ rx,
                                                  const float* __restrict__ vb2,
                                                  const float* __restrict__ degf,
                                                  const float* __restrict__ rci,
                                                  const float* __restrict__ rcj,
                                                  const float* __restrict__ rh,
                                                  const float* __restrict__ g,
                                                  const float* __restrict__ bb,
                                                  float* __restrict__ mx0,
                                                  u16* __restrict__ t1,
                                                  u16* __restrict__ ci1,
                                                  u16* __restrict__ cj1) {
    __shared__ u16 wbuf[128 * LDP];
    __shared__ u16 xt[8][16 * LDP];
    __shared__ float rsum[4][128];
    int tid = threadIdx.x, lane = tid & 63, w = tid >> 6;
    int col = lane & 15, qd = lane >> 4;
    int rowbase = blockIdx.x * 128 + w * 32;
    int b = blockIdx.x >> 3;

    // phase A: x0 = LN(relu(S@Wc0 + rx + deg*vb2)) + mx0 accumulation
    stage_w(wbuf, wb, tid);
    __syncthreads();
    floatx4 xa[2][8] = {};
#pragma unroll
    for (int kb = 0; kb < 4; ++kb) {
        short8 Bv[8];
#pragma unroll
        for (int nt = 0; nt < 8; ++nt) Bv[nt] = sfrag(wbuf, nt * 16, kb, lane);
#pragma unroll
        for (int t = 0; t < 2; ++t) {
            short8 a = gfrag(S, rowbase + t * 16, kb, lane);
#pragma unroll
            for (int nt = 0; nt < 8; ++nt) xa[t][nt] = mfma16(a, Bv[nt], xa[t][nt]);
        }
    }
    float s8[8] = {};
#pragma unroll
    for (int t = 0; t < 2; ++t) {
#pragma unroll
        for (int nt = 0; nt < 8; ++nt) {
            int cg = nt * 16 + col;
            float base = rx[b * 128 + cg], vb = vb2[cg];
#pragma unroll
            for (int r = 0; r < 4; ++r) {
                int row = rowbase + t * 16 + qd * 4 + r;
                xa[t][nt][r] = fmaxf(xa[t][nt][r] + base + degf[row & (NQ_ - 1)] * vb, 0.f);
            }
        }
#pragma unroll
        for (int r = 0; r < 4; ++r) {
            float s = 0.f, s2 = 0.f;
#pragma unroll
            for (int nt = 0; nt < 8; ++nt) { float v = xa[t][nt][r]; s += v; s2 += v * v; }
#pragma unroll
            for (int o = 1; o < 16; o <<= 1) { s += __shfl_xor(s, o, 64); s2 += __shfl_xor(s2, o, 64); }
            float mu = s * (1.f / 128.f), var = s2 * (1.f / 128.f) - mu * mu;
            float rs = rsqrtf(var + 1e-5f);
#pragma unroll
            for (int nt = 0; nt < 8; ++nt) {
                int cg = nt * 16 + col;
                float xv = (xa[t][nt][r] - mu) * rs * g[cg] + bb[cg];
                xa[t][nt][r] = xv;
                s8[nt] += xv;
            }
        }
        tile_store(&xt[w * 2 + t][0], xa[t], lane);
    }
#pragma unroll
    for (int nt = 0; nt < 8; ++nt) {
        s8[nt] += __shfl_xor(s8[nt], 16, 64);
        s8[nt] += __shfl_xor(s8[nt], 32, 64);
    }
    if (lane < 16) {
#pragma unroll
        for (int nt = 0; nt < 8; ++nt) rsum[w][nt * 16 + lane] = s8[nt];
    }
    __syncthreads();
    if (tid < 128) {
        float v = rsum[0][tid] + rsum[1][tid] + rsum[2][tid] + rsum[3][tid];
        atomicAdd(mx0 + b * 128 + tid, v);
    }

    // phases B/C/D: t1 = x@Wf + rh ; ci1 = x@Wd + rci ; cj1 = x@We + rcj
#pragma unroll
    for (int ph = 0; ph < 3; ++ph) {
        const u16* Wsl = wb + ((ph == 0) ? 4 : (ph == 1) ? 2 : 3) * 16384;
        const float* rt = (ph == 0) ? rh : (ph == 1) ? rci : rcj;
        u16* dstg = (ph == 0) ? t1 : (ph == 1) ? ci1 : cj1;
        __syncthreads();
        stage_w(wbuf, Wsl, tid);
        __syncthreads();
        floatx4 ca[2][8] = {};
#pragma unroll
        for (int kb = 0; kb < 4; ++kb) {
            short8 Bv[8];
#pragma unroll
            for (int nt = 0; nt < 8; ++nt) Bv[nt] = sfrag(wbuf, nt * 16, kb, lane);
#pragma unroll
            for (int t = 0; t < 2; ++t) {
                short8 a = sfrag(&xt[w * 2 + t][0], 0, kb, lane);
#pragma unroll
                for (int nt = 0; nt < 8; ++nt) ca[t][nt] = mfma16(a, Bv[nt], ca[t][nt]);
            }
        }
#pragma unroll
        for (int t = 0; t < 2; ++t)
#pragma unroll
            for (int nt = 0; nt < 8; ++nt) {
                float rc = rt[b * 128 + nt * 16 + col];
#pragma unroll
                for (int r = 0; r < 4; ++r) ca[t][nt][r] += rc;
            }
        __syncthreads();
#pragma unroll
        for (int t = 0; t < 2; ++t) tile_store(wbuf + (w * 2 + t) * 16 * LDP, ca[t], lane);
        WVB();
#pragma unroll
        for (int t = 0; t < 2; ++t)
            tile_flush(wbuf + (w * 2 + t) * 16 * LDP, dstg + (size_t)(rowbase + t * 16) * 128, lane);
    }
}

// ---------------------------------------------------------------------------
// node1: x1 = LN(relu(S@Wc1 + t1 + deg*vb2_1));
//        out += mean_q(x1@n2_1); one block per b adds z0+n_b2s+mx0@n2_0/1024
// ---------------------------------------------------------------------------
__global__ __launch_bounds__(256, 2) void k_node1(const u16* __restrict__ S,
                                                  const u16* __restrict__ t1,
                                                  const u16* __restrict__ wb,
                                                  const float* __restrict__ vb2,
                                                  const float* __restrict__ degf,
                                                  const float* __restrict__ g,
                                                  const float* __restrict__ bb,
                                                  const float* __restrict__ z0,
                                                  const float* __restrict__ n_b2,
                                                  const float* __restrict__ mx0,
                                                  float* __restrict__ out) {
    __shared__ u16 wbuf[128 * LDP];
    __shared__ u16 xt[8][16 * LDP];
    __shared__ float rsum[4][128];
    int tid = threadIdx.x, lane = tid & 63, w = tid >> 6;
    int col = lane & 15, qd = lane >> 4;
    int rowbase = blockIdx.x * 128 + w * 32;
    int b = blockIdx.x >> 3;

    // x1 = LN(relu(S@Wc1 + t1 + deg*vb2_1))  (n_b1_1 folded into t1 via rh)
    stage_w(wbuf, wb + 5 * 16384, tid);
    __syncthreads();
    floatx4 xa[2][8] = {};
#pragma unroll
    for (int kb = 0; kb < 4; ++kb) {
        short8 Bv[8];
#pragma unroll
        for (int nt = 0; nt < 8; ++nt) Bv[nt] = sfrag(wbuf, nt * 16, kb, lane);
#pragma unroll
        for (int t = 0; t < 2; ++t) {
            short8 a = gfrag(S, rowbase + t * 16, kb, lane);
#pragma unroll
            for (int nt = 0; nt < 8; ++nt) xa[t][nt] = mfma16(a, Bv[nt], xa[t][nt]);
        }
    }
#pragma unroll
    for (int t = 0; t < 2; ++t) {
#pragma unroll
        for (int nt = 0; nt < 8; ++nt) {
            int cg = nt * 16 + col;
            float vb = vb2[cg];
#pragma unroll
            for (int r = 0; r < 4; ++r) {
                int row = rowbase + t * 16 + qd * 4 + r;
                float tv = bf2f(t1[(size_t)row * 128 + cg]);
                xa[t][nt][r] = fmaxf(xa[t][nt][r] + tv + degf[row & (NQ_ - 1)] * vb, 0.f);
            }
        }
#pragma unroll
        for (int r = 0; r < 4; ++r) {
            float s = 0.f, s2 = 0.f;
#pragma unroll
            for (int nt = 0; nt < 8; ++nt) { float v = xa[t][nt][r]; s += v; s2 += v * v; }
#pragma unroll
            for (int o = 1; o < 16; o <<= 1) { s += __shfl_xor(s, o, 64); s2 += __shfl_xor(s2, o, 64); }
            float mu = s * (1.f / 128.f), var = s2 * (1.f / 128.f) - mu * mu;
            float rs = rsqrtf(var + 1e-5f);
#pragma unroll
            for (int nt = 0; nt < 8; ++nt) {
                int cg = nt * 16 + col;
                xa[t][nt][r] = (xa[t][nt][r] - mu) * rs * g[cg] + bb[cg];
            }
        }
        tile_store(&xt[w * 2 + t][0], xa[t], lane);
    }
    __syncthreads();

    // mean(x1@n2_1) -> out
    stage_w(wbuf, wb + 6 * 16384, tid);
    __syncthreads();
    floatx4 ma[2][8] = {};
#pragma unroll
    for (int kb = 0; kb < 4; ++kb) {
        short8 Bv[8];
#pragma unroll
        for (int nt = 0; nt < 8; ++nt) Bv[nt] = sfrag(wbuf, nt * 16, kb, lane);
#pragma unroll
        for (int t = 0; t < 2; ++t) {
            short8 a = sfrag(&xt[w * 2 + t][0], 0, kb, lane);
#pragma unroll
            for (int nt = 0; nt < 8; ++nt) ma[t][nt] = mfma16(a, Bv[nt], ma[t][nt]);
        }
    }
    float s8[8] = {};
#pragma unroll
    for (int t = 0; t < 2; ++t)
#pragma unroll
        for (int nt = 0; nt < 8; ++nt)
#pragma unroll
            for (int r = 0; r < 4; ++r) s8[nt] += ma[t][nt][r];
#pragma unroll
    for (int nt = 0; nt < 8; ++nt) {
        s8[nt] += __shfl_xor(s8[nt], 16, 64);
        s8[nt] += __shfl_xor(s8[nt], 32, 64);
    }
    if (lane < 16) {
#pragma unroll
        for (int nt = 0; nt < 8; ++nt) rsum[w][nt * 16 + lane] = s8[nt];
    }
    __syncthreads();
    if (tid < 128) {
        float v = rsum[0][tid] + rsum[1][tid] + rsum[2][tid] + rsum[3][tid];
        atomicAdd(out + b * 128 + tid, v * (1.f / 1024.f));
    }

    // fin: out[b] += z0[b] + n_b2_0 + n_b2_1 + mx0[b]@n2_0^T / 1024
    if ((blockIdx.x & 7) == 0 && tid < 128) {
        int c = tid;
        const u16* w2s = wb + 1 * 16384;          // n2_0 bf16 [c][k]
        const float* mx = mx0 + b * 128;
        float s = 0.f;
#pragma unroll 4
        for (int k = 0; k < 128; ++k) s += mx[k] * bf2f(w2s[c * 128 + k]);
        float acc = z0[b * 128 + c] + n_b2[c] + n_b2[128 + c] + s * (1.f / 1024.f);
        atomicAdd(out + b * 128 + c, acc);
    }
}

// ---------------------------------------------------------------------------
extern "C" void kernel_launch(void* const* d_in, const int* in_sizes, int n_in,
                              void* d_out, int out_size, void* d_ws, size_t ws_size,
                              hipStream_t stream) {
    const float* z0   = (const float*)d_in[0];
    const int*   ei   = (const int*)d_in[1];
    const float* attr = (const float*)d_in[2];
    const float* e_w1 = (const float*)d_in[4];
    const float* e_b1 = (const float*)d_in[5];
    const float* e_w2 = (const float*)d_in[6];
    const float* e_b2 = (const float*)d_in[7];
    const float* n_w1 = (const float*)d_in[8];
    const float* n_b1 = (const float*)d_in[9];
    const float* ln_g = (const float*)d_in[10];
    const float* ln_b = (const float*)d_in[11];
    const float* n_w2 = (const float*)d_in[12];
    const float* n_b2 = (const float*)d_in[13];
    float* out = (float*)d_out;

    const size_t H = (size_t)M_ * L_;
    float* f     = (float*)d_ws;
    float* degf  = f;                        // 1024
    float* a_s   = f + 1024;                 // 8192
    float* wl    = a_s + 8192;               // 256
    float* vb2   = wl + 256;                 // 256
    float* rx    = vb2 + 256;                // 8192
    float* rci   = rx + 8192;                // 8192
    float* rcj   = rci + 8192;               // 8192
    float* rh    = rcj + 8192;               // 8192
    float* mx0   = rh + 8192;                // 8192
    int*   ofs   = (int*)(mx0 + 8192);       // 1025 (pad 1056)
    int*   tgt_s = ofs + 1056;               // 8192
    u16*   wb    = (u16*)(tgt_s + 8192);     // 7*16384 u16
    u16*   c0t   = wb + 7 * 16384;           // 8192
    u16*   S     = c0t + 8192;               // H
    u16*   t1    = S + H;                    // H
    u16*   ci1   = t1 + H;                   // H
    u16*   cj1   = ci1 + H;                  // H

    hipMemsetAsync(out, 0, 8192 * sizeof(float), stream);

    k_setup<<<14, 256, 0, stream>>>(ei, attr, z0, e_w1, e_b1, e_w2, e_b2,
                                    n_w1, n_b1, n_w2, n_b2,
                                    ofs, tgt_s, a_s, degf, wb, wl, vb2,
                                    rx, rci, rcj, rh, mx0, c0t);

    k_edge<true><<<2048, 256, 0, stream>>>(c0t, nullptr, ofs, tgt_s, a_s, wl, S);

    k_node0<<<512, 256, 0, stream>>>(S, wb, rx, vb2, degf, rci, rcj, rh,
                                     ln_g, ln_b, mx0, t1, ci1, cj1);

    k_edge<false><<<2048, 256, 0, stream>>>(ci1, cj1, ofs, tgt_s, a_s, wl + 128, S);

    k_node1<<<512, 256, 0, stream>>>(S, t1, wb, vb2 + 128, degf,
                                     ln_g + 128, ln_b + 128, z0, n_b2, mx0, out);
}